// Round 3
// baseline (8407.925 us; speedup 1.0000x reference)
//
#include <hip/hip_runtime.h>
#include <hip/hip_bf16.h>

#define N_IN  80
#define N_OUT 25
#define BOS   4093

typedef __attribute__((ext_vector_type(8))) short bf16x8;
typedef __attribute__((ext_vector_type(4))) float f32x4;

__device__ inline unsigned short f2bf(float f) {
    unsigned int u = __builtin_bit_cast(unsigned int, f);
    unsigned int r = (u + 0x7fffu + ((u >> 16) & 1u)) >> 16;
    return (unsigned short)r;
}
__device__ inline float sigf(float x) { return 1.f / (1.f + expf(-x)); }

// ---------------------------------------------------------------------------
// grid barrier (sense-reversal, agent scope). All WGs must call same # times.
// ---------------------------------------------------------------------------
__device__ __forceinline__ void gbar(int* cnt, int* gen, int nwg, int& lgen)
{
    __syncthreads();
    if (threadIdx.x == 0) {
        __threadfence();   // release our writes to agent scope
        int g = lgen;
        int t = __hip_atomic_fetch_add(cnt, 1, __ATOMIC_ACQ_REL, __HIP_MEMORY_SCOPE_AGENT);
        if (t == nwg - 1) {
            __hip_atomic_store(cnt, 0, __ATOMIC_RELAXED, __HIP_MEMORY_SCOPE_AGENT);
            __hip_atomic_store(gen, g + 1, __ATOMIC_RELEASE, __HIP_MEMORY_SCOPE_AGENT);
        } else {
            while (__hip_atomic_load(gen, __ATOMIC_ACQUIRE, __HIP_MEMORY_SCOPE_AGENT) < g + 1) {
                __builtin_amdgcn_s_sleep(2);
            }
        }
        lgen = g + 1;
    }
    __syncthreads();
    __threadfence();       // acquire side
}

// ---------------------------------------------------------------------------
// bf16 MFMA GEMM (from round 2, verified): C = act(A @ W^T + bias)
// ---------------------------------------------------------------------------
template<int AFP32, int OUT_BF, int ACT>
__global__ __launch_bounds__(256)
void gemm_mfma(const void* __restrict__ Ap, int lda,
               const unsigned short* __restrict__ W, int ldw,
               const float* __restrict__ bias,
               void* __restrict__ Cp, int ldc, int K)
{
    __shared__ short Abuf[128 * 32];
    __shared__ short Wbuf[128 * 32];
    const int tid  = threadIdx.x;
    const int lane = tid & 63;
    const int wave = tid >> 6;
    const int wr = wave >> 1, wc = wave & 1;
    const int l15 = lane & 15, kg = lane >> 4;
    const int m0 = blockIdx.y * 128, n0 = blockIdx.x * 128;

    const float* Af = (const float*)Ap;
    const unsigned short* Ab = (const unsigned short*)Ap;

    f32x4 acc[4][4];
#pragma unroll
    for (int i = 0; i < 4; ++i)
#pragma unroll
        for (int j = 0; j < 4; ++j) acc[i][j] = f32x4{0.f, 0.f, 0.f, 0.f};

    const bf16x8* Av = (const bf16x8*)Abuf;
    const bf16x8* Wv = (const bf16x8*)Wbuf;

    for (int k0 = 0; k0 < K; k0 += 32) {
#pragma unroll
        for (int cc = 0; cc < 2; ++cc) {
            int c = tid + cc * 256;
            int row = c >> 2, k8 = (c & 3) * 8;
            if (AFP32) {
                const float* src = &Af[(size_t)(m0 + row) * lda + k0 + k8];
                float4 v0 = *reinterpret_cast<const float4*>(src);
                float4 v1 = *reinterpret_cast<const float4*>(src + 4);
                bf16x8 s;
                s[0] = (short)f2bf(v0.x); s[1] = (short)f2bf(v0.y);
                s[2] = (short)f2bf(v0.z); s[3] = (short)f2bf(v0.w);
                s[4] = (short)f2bf(v1.x); s[5] = (short)f2bf(v1.y);
                s[6] = (short)f2bf(v1.z); s[7] = (short)f2bf(v1.w);
                *reinterpret_cast<bf16x8*>(&Abuf[row * 32 + k8]) = s;
            } else {
                *reinterpret_cast<bf16x8*>(&Abuf[row * 32 + k8]) =
                    *reinterpret_cast<const bf16x8*>(&Ab[(size_t)(m0 + row) * lda + k0 + k8]);
            }
            *reinterpret_cast<bf16x8*>(&Wbuf[row * 32 + k8]) =
                *reinterpret_cast<const bf16x8*>(&W[(size_t)(n0 + row) * ldw + k0 + k8]);
        }
        __syncthreads();
        bf16x8 a[4], b[4];
#pragma unroll
        for (int i = 0; i < 4; ++i) a[i] = Av[(wr * 64 + i * 16 + l15) * 4 + kg];
#pragma unroll
        for (int j = 0; j < 4; ++j) b[j] = Wv[(wc * 64 + j * 16 + l15) * 4 + kg];
#pragma unroll
        for (int i = 0; i < 4; ++i)
#pragma unroll
            for (int j = 0; j < 4; ++j)
                acc[i][j] = __builtin_amdgcn_mfma_f32_16x16x32_bf16(a[i], b[j], acc[i][j], 0, 0, 0);
        __syncthreads();
    }

    float* Cf = (float*)Cp;
    unsigned short* Cb = (unsigned short*)Cp;
#pragma unroll
    for (int i = 0; i < 4; ++i) {
#pragma unroll
        for (int j = 0; j < 4; ++j) {
            int n = n0 + wc * 64 + j * 16 + l15;
            float bv = bias[n];
#pragma unroll
            for (int r = 0; r < 4; ++r) {
                int m = m0 + wr * 64 + i * 16 + kg * 4 + r;
                float v = acc[i][j][r] + bv;
                if (ACT == 1) v = v > 0.f ? v : 0.01f * v;
                if (OUT_BF) Cb[(size_t)m * ldc + n] = f2bf(v);
                else        Cf[(size_t)m * ldc + n] = v;
            }
        }
    }
}

// ---------------------------------------------------------------------------
// Persistent recurrence kernel: 105 iterations.
//   enc step i (WGs 0..31):  h_enc[i] = GRU(h_enc[i-1], gi_enc[i])
//   dec1 step i-1 (WGs 32..95, for 1<=i<=80): gi = enc_out[i-1]@wihE^T,
//      gh = hD@whh^T, gates -> hD
// One grid barrier per iteration. Gate triples (r,z,n cols) owned per-wave.
// ---------------------------------------------------------------------------
__global__ __launch_bounds__(256)
void recur_persist(const float* __restrict__ enc_gi,
                   const float* __restrict__ enc_bih, const float* __restrict__ enc_bhh,
                   const unsigned short* __restrict__ encwhh_bf,
                   const unsigned short* __restrict__ decwih_bf,
                   const unsigned short* __restrict__ decwhh_bf,
                   const float* __restrict__ dec_bih, const float* __restrict__ dec_bhh,
                   const unsigned short* __restrict__ h0b,
                   float* __restrict__ enc_out, unsigned short* __restrict__ encout_bf,
                   float* __restrict__ hDf, unsigned short* __restrict__ hDb,
                   int* bar_cnt, int* bar_gen)
{
    const int g = blockIdx.x;
    const int tid = threadIdx.x, w = tid >> 6, lane = tid & 63;
    const int l15 = lane & 15, kg = lane >> 4;
    int lgen = 0;

    if (g < 32) {
        const int cg = g >> 1, rh = g & 1;
        const int mb = rh * 64 + w * 16;
        int wrow[6];
#pragma unroll
        for (int ct = 0; ct < 6; ++ct) wrow[ct] = (ct >> 1) * 512 + cg * 32 + (ct & 1) * 16 + l15;

        for (int i = 0; i < 105; ++i) {
            const unsigned short* A = (i == 0) ? h0b : encout_bf + (size_t)(i - 1) * 65536;
            f32x4 acc[6];
#pragma unroll
            for (int ct = 0; ct < 6; ++ct) acc[ct] = f32x4{0.f, 0.f, 0.f, 0.f};
#pragma unroll 4
            for (int ks = 0; ks < 16; ++ks) {
                bf16x8 a = *(const bf16x8*)&A[(size_t)(mb + l15) * 512 + ks * 32 + kg * 8];
#pragma unroll
                for (int ct = 0; ct < 6; ++ct) {
                    bf16x8 bv = *(const bf16x8*)&encwhh_bf[(size_t)wrow[ct] * 512 + ks * 32 + kg * 8];
                    acc[ct] = __builtin_amdgcn_mfma_f32_16x16x32_bf16(a, bv, acc[ct], 0, 0, 0);
                }
            }
#pragma unroll
            for (int jh = 0; jh < 2; ++jh) {
                int jc = cg * 32 + jh * 16 + l15;
                float bhr = enc_bhh[jc], bhz = enc_bhh[512 + jc], bhn = enc_bhh[1024 + jc];
#pragma unroll
                for (int rr = 0; rr < 4; ++rr) {
                    int br = mb + kg * 4 + rr;
                    float gr_, gz_, gn_;
                    if (i < 80) {
                        const float* gp = enc_gi + ((size_t)i * 128 + br) * 1536 + jc;
                        gr_ = gp[0]; gz_ = gp[512]; gn_ = gp[1024];
                    } else {
                        gr_ = enc_bih[jc]; gz_ = enc_bih[512 + jc]; gn_ = enc_bih[1024 + jc];
                    }
                    float hp = (i == 0) ? 0.f : enc_out[(size_t)(i - 1) * 65536 + br * 512 + jc];
                    float r = sigf(gr_ + bhr + acc[jh][rr]);
                    float z = sigf(gz_ + bhz + acc[2 + jh][rr]);
                    float n = tanhf(gn_ + r * (acc[4 + jh][rr] + bhn));
                    float v = (1.f - z) * n + z * hp;
                    enc_out[(size_t)i * 65536 + br * 512 + jc] = v;
                    encout_bf[(size_t)i * 65536 + br * 512 + jc] = f2bf(v);
                }
            }
            gbar(bar_cnt, bar_gen, 96, lgen);
        }
    } else {
        const int gl = g - 32, cg = gl >> 2, rq = gl & 3;
        const int rt = w >> 1, cs = w & 1;
        const int mb = rq * 32 + rt * 16;
        int wrow[3];
#pragma unroll
        for (int t = 0; t < 3; ++t) wrow[t] = t * 512 + cg * 32 + cs * 16 + l15;
        const int jc = cg * 32 + cs * 16 + l15;

        for (int i = 0; i < 105; ++i) {
            if (i >= 1 && i <= 80) {
                f32x4 agi[3], agh[3];
#pragma unroll
                for (int t = 0; t < 3; ++t) { agi[t] = f32x4{0.f,0.f,0.f,0.f}; agh[t] = f32x4{0.f,0.f,0.f,0.f}; }
                const unsigned short* A1 = encout_bf + (size_t)(i - 1) * 65536;
#pragma unroll 4
                for (int ks = 0; ks < 16; ++ks) {
                    bf16x8 a = *(const bf16x8*)&A1[(size_t)(mb + l15) * 512 + ks * 32 + kg * 8];
#pragma unroll
                    for (int t = 0; t < 3; ++t) {
                        bf16x8 bv = *(const bf16x8*)&decwih_bf[(size_t)wrow[t] * 1536 + 1024 + ks * 32 + kg * 8];
                        agi[t] = __builtin_amdgcn_mfma_f32_16x16x32_bf16(a, bv, agi[t], 0, 0, 0);
                    }
                }
                const unsigned short* A2 = (i == 1) ? h0b : hDb + (size_t)((i - 1) & 1) * 65536;
#pragma unroll 4
                for (int ks = 0; ks < 16; ++ks) {
                    bf16x8 a = *(const bf16x8*)&A2[(size_t)(mb + l15) * 512 + ks * 32 + kg * 8];
#pragma unroll
                    for (int t = 0; t < 3; ++t) {
                        bf16x8 bv = *(const bf16x8*)&decwhh_bf[(size_t)wrow[t] * 512 + ks * 32 + kg * 8];
                        agh[t] = __builtin_amdgcn_mfma_f32_16x16x32_bf16(a, bv, agh[t], 0, 0, 0);
                    }
                }
                float bir = dec_bih[jc], bhr = dec_bhh[jc];
                float biz = dec_bih[512 + jc], bhz = dec_bhh[512 + jc];
                float bin_ = dec_bih[1024 + jc], bhn = dec_bhh[1024 + jc];
                const float* hpf = hDf + (size_t)((i - 1) & 1) * 65536;
                float* hof = hDf + (size_t)(i & 1) * 65536;
                unsigned short* hob = hDb + (size_t)(i & 1) * 65536;
#pragma unroll
                for (int rr = 0; rr < 4; ++rr) {
                    int br = mb + kg * 4 + rr;
                    float hp = (i == 1) ? 0.f : hpf[br * 512 + jc];
                    float r = sigf(agi[0][rr] + bir + agh[0][rr] + bhr);
                    float z = sigf(agi[1][rr] + biz + agh[1][rr] + bhz);
                    float n = tanhf(agi[2][rr] + bin_ + r * (agh[2][rr] + bhn));
                    float v = (1.f - z) * n + z * hp;
                    hof[br * 512 + jc] = v;
                    hob[br * 512 + jc] = f2bf(v);
                }
            }
            gbar(bar_cnt, bar_gen, 96, lgen);
        }
    }
}

// ---------------------------------------------------------------------------
// attention for batch b: s=tanh(encA . h), softmax, c -> c_bf (bf16)
// ---------------------------------------------------------------------------
__device__ void attention(int b, const float* __restrict__ hvec,
                          const float* __restrict__ enc_out,
                          unsigned short* __restrict__ c_bf,
                          float* hsh, float* ssh)
{
    const int tid = threadIdx.x;
    hsh[tid] = hvec[(size_t)b * 512 + tid];
    hsh[256 + tid] = hvec[(size_t)b * 512 + 256 + tid];
    __syncthreads();
    const int wv = tid >> 6, lane = tid & 63;
    for (int i = wv; i < 80; i += 4) {
        const float* row = enc_out + (size_t)i * 65536 + b * 512;
        float p = 0.f;
#pragma unroll
        for (int q = 0; q < 8; ++q) p += row[lane + 64 * q] * hsh[lane + 64 * q];
#pragma unroll
        for (int off = 32; off > 0; off >>= 1) p += __shfl_xor(p, off, 64);
        if (lane == 0) ssh[i] = tanhf(p);
    }
    __syncthreads();
    if (tid == 0) {
        float mx = -1e30f;
        for (int i = 0; i < 80; ++i) mx = fmaxf(mx, ssh[i]);
        float s = 0.f;
        for (int i = 0; i < 80; ++i) { float e = expf(ssh[i] - mx); ssh[i] = e; s += e; }
        ssh[80] = 1.0f / s;
    }
    __syncthreads();
    float inv = ssh[80];
    for (int hc = tid; hc < 512; hc += 256) {
        float acc = 0.f;
        for (int i = 0; i < 80; ++i) acc += ssh[i] * enc_out[(size_t)i * 65536 + b * 512 + hc];
        c_bf[(size_t)b * 512 + hc] = f2bf(acc * inv);
    }
    __syncthreads();
}

// ---------------------------------------------------------------------------
// Persistent decoder: 25 steps, 3 barriers each.
// ---------------------------------------------------------------------------
__global__ __launch_bounds__(256)
void decode_persist(const float* __restrict__ enc_out, const unsigned short* __restrict__ encout_bf,
                    const unsigned short* __restrict__ decwih_bf, const unsigned short* __restrict__ decwhh_bf,
                    const float* __restrict__ dec_bih, const float* __restrict__ dec_bhh,
                    const unsigned short* __restrict__ outw_bf, const float* __restrict__ out_b,
                    const float* __restrict__ embed, const int* __restrict__ tgt,
                    const float* __restrict__ hDf, const unsigned short* __restrict__ hDb,
                    float* __restrict__ hCf, unsigned short* __restrict__ hCb,
                    unsigned short* __restrict__ d_bf, unsigned short* __restrict__ c_bf,
                    float* __restrict__ logits, float* __restrict__ out,
                    int* bar_cnt, int* bar_gen)
{
    __shared__ float hsh[512];
    __shared__ float ssh[84];
    __shared__ float rmax[256];
    __shared__ int   rarg[256];
    __shared__ float rsum[256];

    const int g = blockIdx.x;          // 0..127
    const int tid = threadIdx.x, w = tid >> 6, lane = tid & 63;
    const int l15 = lane & 15, kg = lane >> 4;
    int lgen = 0;
    float loss_acc = 0.f;

    // ---- pre-phase: attention_0 from alpha; d_0 = embed[BOS]
    attention(g, hDf, enc_out, c_bf, hsh, ssh);
    for (int t = tid; t < 512; t += 256)
        d_bf[(size_t)g * 512 + t] = f2bf(embed[(size_t)BOS * 512 + t]);
    gbar(bar_cnt, bar_gen, 128, lgen);

    for (int j = 0; j < 25; ++j) {
        const float* h_in_f = (j == 0) ? hDf : hCf + (size_t)((j - 1) & 1) * 65536;
        const unsigned short* h_in_b = (j == 0) ? hDb : hCb + (size_t)((j - 1) & 1) * 65536;
        float* h_out_f = hCf + (size_t)(j & 1) * 65536;
        unsigned short* h_out_b = hCb + (size_t)(j & 1) * 65536;

        // ---- P1: GRU step j (WGs 0..63)
        if (g < 64) {
            const int cg = g >> 2, rq = g & 3;
            const int rt = w >> 1, cs = w & 1;
            const int mb = rq * 32 + rt * 16;
            const int jc = cg * 32 + cs * 16 + l15;
            int wrow[3];
#pragma unroll
            for (int t = 0; t < 3; ++t) wrow[t] = t * 512 + cg * 32 + cs * 16 + l15;

            f32x4 agi[3], agh[3];
#pragma unroll
            for (int t = 0; t < 3; ++t) { agi[t] = f32x4{0.f,0.f,0.f,0.f}; agh[t] = f32x4{0.f,0.f,0.f,0.f}; }

            const unsigned short* segA[3] = { d_bf, encout_bf + (size_t)(80 + j) * 65536, c_bf };
#pragma unroll
            for (int s = 0; s < 3; ++s) {
                const unsigned short* A = segA[s];
                const int kofs = s * 512;
#pragma unroll 4
                for (int ks = 0; ks < 16; ++ks) {
                    bf16x8 a = *(const bf16x8*)&A[(size_t)(mb + l15) * 512 + ks * 32 + kg * 8];
#pragma unroll
                    for (int t = 0; t < 3; ++t) {
                        bf16x8 bv = *(const bf16x8*)&decwih_bf[(size_t)wrow[t] * 1536 + kofs + ks * 32 + kg * 8];
                        agi[t] = __builtin_amdgcn_mfma_f32_16x16x32_bf16(a, bv, agi[t], 0, 0, 0);
                    }
                }
            }
#pragma unroll 4
            for (int ks = 0; ks < 16; ++ks) {
                bf16x8 a = *(const bf16x8*)&h_in_b[(size_t)(mb + l15) * 512 + ks * 32 + kg * 8];
#pragma unroll
                for (int t = 0; t < 3; ++t) {
                    bf16x8 bv = *(const bf16x8*)&decwhh_bf[(size_t)wrow[t] * 512 + ks * 32 + kg * 8];
                    agh[t] = __builtin_amdgcn_mfma_f32_16x16x32_bf16(a, bv, agh[t], 0, 0, 0);
                }
            }
            float bir = dec_bih[jc], bhr = dec_bhh[jc];
            float biz = dec_bih[512 + jc], bhz = dec_bhh[512 + jc];
            float bin_ = dec_bih[1024 + jc], bhn = dec_bhh[1024 + jc];
#pragma unroll
            for (int rr = 0; rr < 4; ++rr) {
                int br = mb + kg * 4 + rr;
                float hp = h_in_f[(size_t)br * 512 + jc];
                float r = sigf(agi[0][rr] + bir + agh[0][rr] + bhr);
                float z = sigf(agi[1][rr] + biz + agh[1][rr] + bhz);
                float n = tanhf(agi[2][rr] + bin_ + r * (agh[2][rr] + bhn));
                float v = (1.f - z) * n + z * hp;
                h_out_f[(size_t)br * 512 + jc] = v;
                h_out_b[(size_t)br * 512 + jc] = f2bf(v);
            }
        }
        gbar(bar_cnt, bar_gen, 128, lgen);

        // ---- P2: logits_j (all WGs) + attention_{j+1}
        {
            const int n0 = g * 32;
            f32x4 acc[2][2];
#pragma unroll
            for (int mt = 0; mt < 2; ++mt)
#pragma unroll
                for (int nt = 0; nt < 2; ++nt) acc[mt][nt] = f32x4{0.f,0.f,0.f,0.f};
#pragma unroll 4
            for (int ks = 0; ks < 16; ++ks) {
                bf16x8 a0 = *(const bf16x8*)&h_out_b[(size_t)(w * 32 + l15) * 512 + ks * 32 + kg * 8];
                bf16x8 a1 = *(const bf16x8*)&h_out_b[(size_t)(w * 32 + 16 + l15) * 512 + ks * 32 + kg * 8];
                bf16x8 b0 = *(const bf16x8*)&outw_bf[(size_t)(n0 + l15) * 512 + ks * 32 + kg * 8];
                bf16x8 b1 = *(const bf16x8*)&outw_bf[(size_t)(n0 + 16 + l15) * 512 + ks * 32 + kg * 8];
                acc[0][0] = __builtin_amdgcn_mfma_f32_16x16x32_bf16(a0, b0, acc[0][0], 0, 0, 0);
                acc[0][1] = __builtin_amdgcn_mfma_f32_16x16x32_bf16(a0, b1, acc[0][1], 0, 0, 0);
                acc[1][0] = __builtin_amdgcn_mfma_f32_16x16x32_bf16(a1, b0, acc[1][0], 0, 0, 0);
                acc[1][1] = __builtin_amdgcn_mfma_f32_16x16x32_bf16(a1, b1, acc[1][1], 0, 0, 0);
            }
#pragma unroll
            for (int mt = 0; mt < 2; ++mt)
#pragma unroll
                for (int nt = 0; nt < 2; ++nt) {
                    int n = n0 + nt * 16 + l15;
                    float bv = out_b[n];
#pragma unroll
                    for (int rr = 0; rr < 4; ++rr) {
                        int m = w * 32 + mt * 16 + kg * 4 + rr;
                        logits[(size_t)m * 4096 + n] = acc[mt][nt][rr] + bv;
                    }
                }
            if (j < 24) attention(g, h_out_f, enc_out, c_bf, hsh, ssh);
        }
        gbar(bar_cnt, bar_gen, 128, lgen);

        // ---- P3: loss_j + argmax feedback (WG g handles batch b=g)
        {
            const int b = g;
            const float* lg = logits + (size_t)b * 4096;
            float lmax = -1e30f; int larg = 0;
            for (int v = tid; v < 4096; v += 256) {
                float f = lg[v];
                if (f > lmax) { lmax = f; larg = v; }
            }
            rmax[tid] = lmax; rarg[tid] = larg;
            __syncthreads();
            for (int s = 128; s > 0; s >>= 1) {
                if (tid < s) {
                    float o = rmax[tid + s]; int oi = rarg[tid + s];
                    if (o > rmax[tid] || (o == rmax[tid] && oi < rarg[tid])) { rmax[tid] = o; rarg[tid] = oi; }
                }
                __syncthreads();
            }
            float gmax = rmax[0]; int garg = rarg[0];
            float s = 0.f;
            for (int v = tid; v < 4096; v += 256) s += expf(lg[v] - gmax);
            rsum[tid] = s;
            __syncthreads();
            for (int t = 128; t > 0; t >>= 1) { if (tid < t) rsum[tid] += rsum[tid + t]; __syncthreads(); }
            if (tid == 0) {
                float lse = gmax + logf(rsum[0]);
                int tj = tgt[b * 25 + j];
                loss_acc += -(lg[tj] - lse);
            }
            for (int t = tid; t < 512; t += 256)
                d_bf[(size_t)b * 512 + t] = f2bf(embed[(size_t)garg * 512 + t]);
            __syncthreads();
        }
        gbar(bar_cnt, bar_gen, 128, lgen);
    }

    if (tid == 0) atomicAdd(out, loss_acc * (1.0f / 3200.0f));
}

// fp32 -> bf16 cast (n multiple of 1024)
__global__ void cast_f2b(const float* __restrict__ in, unsigned short* __restrict__ out, int n)
{
    int i = (blockIdx.x * 256 + threadIdx.x) * 4;
    if (i < n) {
        float4 v = *reinterpret_cast<const float4*>(&in[i]);
        out[i + 0] = f2bf(v.x); out[i + 1] = f2bf(v.y);
        out[i + 2] = f2bf(v.z); out[i + 3] = f2bf(v.w);
    }
}

// ---------------------------------------------------------------------------
extern "C" void kernel_launch(void* const* d_in, const int* in_sizes, int n_in,
                              void* d_out, int out_size, void* d_ws, size_t ws_size,
                              hipStream_t stream)
{
    const float* feats   = (const float*)d_in[0];
    const float* fc_w    = (const float*)d_in[1];
    const float* fc_b    = (const float*)d_in[2];
    const float* enc_wih = (const float*)d_in[3];
    const float* enc_whh = (const float*)d_in[4];
    const float* enc_bih = (const float*)d_in[5];
    const float* enc_bhh = (const float*)d_in[6];
    const float* dec_wih = (const float*)d_in[7];
    const float* dec_whh = (const float*)d_in[8];
    const float* dec_bih = (const float*)d_in[9];
    const float* dec_bhh = (const float*)d_in[10];
    const float* out_w   = (const float*)d_in[11];
    const float* out_b   = (const float*)d_in[12];
    const float* embed   = (const float*)d_in[13];
    const int*   tgt     = (const int*)d_in[14];

    float* ws = (float*)d_ws;
    size_t off = 0;
    auto afl = [&](size_t n) { float* r = ws + off; off += n; return r; };

    float* enc_gi            = afl(15728640);              // [80][128][1536] fp32 (incl bih)
    float* enc_out           = afl(6881280);               // [105][128][512] fp32
    unsigned short* encout_bf = (unsigned short*)afl(3440640);
    unsigned short* xp_bf     = (unsigned short*)afl(2621440);
    unsigned short* fcw_bf    = (unsigned short*)afl(1048576);
    unsigned short* encwih_bf = (unsigned short*)afl(393216);
    unsigned short* encwhh_bf = (unsigned short*)afl(393216);
    unsigned short* decwih_bf = (unsigned short*)afl(1179648);  // full 1536x1536
    unsigned short* decwhh_bf = (unsigned short*)afl(393216);
    unsigned short* outw_bf   = (unsigned short*)afl(1048576);
    unsigned short* h0b       = (unsigned short*)afl(32768);    // zeros bf16
    float* hDf               = afl(131072);                // [2][128][512]
    unsigned short* hDb       = (unsigned short*)afl(65536);
    float* hCf               = afl(131072);
    unsigned short* hCb       = (unsigned short*)afl(65536);
    unsigned short* d_bf      = (unsigned short*)afl(32768);
    unsigned short* c_bf      = (unsigned short*)afl(32768);
    float* logits            = afl(524288);
    int*   bar               = (int*)afl(16);

    hipMemsetAsync(h0b, 0, 65536 * sizeof(unsigned short), stream);
    hipMemsetAsync(bar, 0, 16 * sizeof(int), stream);
    hipMemsetAsync(d_out, 0, sizeof(float), stream);

    cast_f2b<<<2048, 256, 0, stream>>>(fc_w, fcw_bf, 2097152);
    cast_f2b<<<768, 256, 0, stream>>>(enc_wih, encwih_bf, 786432);
    cast_f2b<<<768, 256, 0, stream>>>(enc_whh, encwhh_bf, 786432);
    cast_f2b<<<2304, 256, 0, stream>>>(dec_wih, decwih_bf, 2359296);
    cast_f2b<<<768, 256, 0, stream>>>(dec_whh, decwhh_bf, 786432);
    cast_f2b<<<2048, 256, 0, stream>>>(out_w, outw_bf, 2097152);

    // fc: xp_bf = leaky_relu(feats @ fc_w^T + fc_b)   M=10240 K=4096 N=512
    gemm_mfma<1, 1, 1><<<dim3(4, 80), 256, 0, stream>>>(feats, 4096, fcw_bf, 4096, fc_b, xp_bf, 512, 4096);
    // enc gi (t<80): xp @ enc_wih^T + enc_bih   M=10240 K=512 N=1536
    gemm_mfma<0, 0, 0><<<dim3(12, 80), 256, 0, stream>>>(xp_bf, 512, encwih_bf, 512, enc_bih, enc_gi, 1536, 512);

    recur_persist<<<96, 256, 0, stream>>>(enc_gi, enc_bih, enc_bhh, encwhh_bf,
                                          decwih_bf, decwhh_bf, dec_bih, dec_bhh,
                                          h0b, enc_out, encout_bf, hDf, hDb,
                                          bar + 0, bar + 1);

    decode_persist<<<128, 256, 0, stream>>>(enc_out, encout_bf, decwih_bf, decwhh_bf,
                                            dec_bih, dec_bhh, outw_bf, out_b,
                                            embed, tgt, hDf, hDb, hCf, hCb,
                                            d_bf, c_bf, logits, (float*)d_out,
                                            bar + 2, bar + 3);
}

// Round 4
// 8017.130 us; speedup vs baseline: 1.0487x; 1.0487x over previous
//
#include <hip/hip_runtime.h>
#include <hip/hip_bf16.h>

#define N_IN  80
#define N_OUT 25
#define BOS   4093

typedef __attribute__((ext_vector_type(8))) short bf16x8;
typedef __attribute__((ext_vector_type(4))) float f32x4;

__device__ inline unsigned short f2bf(float f) {
    unsigned int u = __builtin_bit_cast(unsigned int, f);
    unsigned int r = (u + 0x7fffu + ((u >> 16) & 1u)) >> 16;
    return (unsigned short)r;
}
__device__ inline float bf2f(unsigned short s) {
    return __builtin_bit_cast(float, (unsigned int)s << 16);
}
__device__ inline float sigf(float x) { return 1.f / (1.f + expf(-x)); }

// ---------------------------------------------------------------------------
// Flag-based grid barrier: no atomic RMW contention.
// Each WG g>0 release-stores flags[g*32]=target; WG 0's threads poll all
// flags in parallel, then WG 0 publishes gen=target; others acquire-poll gen.
// ---------------------------------------------------------------------------
__device__ __forceinline__ void gbar2(int* flags, int* gen, int nwg, int target)
{
    __syncthreads();
    const int g = blockIdx.x, tid = threadIdx.x;
    if (g == 0) {
        if (tid == 0) __threadfence();
        __syncthreads();
        if (tid >= 1 && tid < nwg) {
            while (__hip_atomic_load(&flags[tid * 32], __ATOMIC_RELAXED, __HIP_MEMORY_SCOPE_AGENT) < target)
                __builtin_amdgcn_s_sleep(1);
        }
        __syncthreads();
        if (tid == 0) {
            __threadfence();
            __hip_atomic_store(gen, target, __ATOMIC_RELEASE, __HIP_MEMORY_SCOPE_AGENT);
        }
    } else {
        if (tid == 0) {
            __threadfence();
            __hip_atomic_store(&flags[g * 32], target, __ATOMIC_RELEASE, __HIP_MEMORY_SCOPE_AGENT);
            while (__hip_atomic_load(gen, __ATOMIC_ACQUIRE, __HIP_MEMORY_SCOPE_AGENT) < target)
                __builtin_amdgcn_s_sleep(1);
        }
    }
    __syncthreads();
    __threadfence();
}

// ---------------------------------------------------------------------------
// bf16 MFMA GEMM: C = act(A @ W^T + bias)
// ---------------------------------------------------------------------------
template<int AFP32, int OUT_BF, int ACT>
__global__ __launch_bounds__(256)
void gemm_mfma(const void* __restrict__ Ap, int lda,
               const unsigned short* __restrict__ W, int ldw,
               const float* __restrict__ bias,
               void* __restrict__ Cp, int ldc, int K)
{
    __shared__ short Abuf[128 * 32];
    __shared__ short Wbuf[128 * 32];
    const int tid  = threadIdx.x;
    const int lane = tid & 63;
    const int wave = tid >> 6;
    const int wr = wave >> 1, wc = wave & 1;
    const int l15 = lane & 15, kg = lane >> 4;
    const int m0 = blockIdx.y * 128, n0 = blockIdx.x * 128;

    const float* Af = (const float*)Ap;
    const unsigned short* Ab = (const unsigned short*)Ap;

    f32x4 acc[4][4];
#pragma unroll
    for (int i = 0; i < 4; ++i)
#pragma unroll
        for (int j = 0; j < 4; ++j) acc[i][j] = f32x4{0.f, 0.f, 0.f, 0.f};

    const bf16x8* Av = (const bf16x8*)Abuf;
    const bf16x8* Wv = (const bf16x8*)Wbuf;

    for (int k0 = 0; k0 < K; k0 += 32) {
#pragma unroll
        for (int cc = 0; cc < 2; ++cc) {
            int c = tid + cc * 256;
            int row = c >> 2, k8 = (c & 3) * 8;
            if (AFP32) {
                const float* src = &Af[(size_t)(m0 + row) * lda + k0 + k8];
                float4 v0 = *reinterpret_cast<const float4*>(src);
                float4 v1 = *reinterpret_cast<const float4*>(src + 4);
                bf16x8 s;
                s[0] = (short)f2bf(v0.x); s[1] = (short)f2bf(v0.y);
                s[2] = (short)f2bf(v0.z); s[3] = (short)f2bf(v0.w);
                s[4] = (short)f2bf(v1.x); s[5] = (short)f2bf(v1.y);
                s[6] = (short)f2bf(v1.z); s[7] = (short)f2bf(v1.w);
                *reinterpret_cast<bf16x8*>(&Abuf[row * 32 + k8]) = s;
            } else {
                *reinterpret_cast<bf16x8*>(&Abuf[row * 32 + k8]) =
                    *reinterpret_cast<const bf16x8*>(&Ab[(size_t)(m0 + row) * lda + k0 + k8]);
            }
            *reinterpret_cast<bf16x8*>(&Wbuf[row * 32 + k8]) =
                *reinterpret_cast<const bf16x8*>(&W[(size_t)(n0 + row) * ldw + k0 + k8]);
        }
        __syncthreads();
        bf16x8 a[4], b[4];
#pragma unroll
        for (int i = 0; i < 4; ++i) a[i] = Av[(wr * 64 + i * 16 + l15) * 4 + kg];
#pragma unroll
        for (int j = 0; j < 4; ++j) b[j] = Wv[(wc * 64 + j * 16 + l15) * 4 + kg];
#pragma unroll
        for (int i = 0; i < 4; ++i)
#pragma unroll
            for (int j = 0; j < 4; ++j)
                acc[i][j] = __builtin_amdgcn_mfma_f32_16x16x32_bf16(a[i], b[j], acc[i][j], 0, 0, 0);
        __syncthreads();
    }

    float* Cf = (float*)Cp;
    unsigned short* Cb = (unsigned short*)Cp;
#pragma unroll
    for (int i = 0; i < 4; ++i) {
#pragma unroll
        for (int j = 0; j < 4; ++j) {
            int n = n0 + wc * 64 + j * 16 + l15;
            float bv = bias[n];
#pragma unroll
            for (int r = 0; r < 4; ++r) {
                int m = m0 + wr * 64 + i * 16 + kg * 4 + r;
                float v = acc[i][j][r] + bv;
                if (ACT == 1) v = v > 0.f ? v : 0.01f * v;
                if (OUT_BF) Cb[(size_t)m * ldc + n] = f2bf(v);
                else        Cf[(size_t)m * ldc + n] = v;
            }
        }
    }
}

// ---------------------------------------------------------------------------
// Persistent recurrence kernel: 105 iterations, 1 barrier each.
// WGs 0..31: encoder GRU step i.  WGs 32..95: dec1 step i-1 (1<=i<=80).
// ---------------------------------------------------------------------------
__global__ __launch_bounds__(256)
void recur_persist(const float* __restrict__ enc_gi,
                   const float* __restrict__ enc_bih, const float* __restrict__ enc_bhh,
                   const unsigned short* __restrict__ encwhh_bf,
                   const unsigned short* __restrict__ decwih_bf,
                   const unsigned short* __restrict__ decwhh_bf,
                   const float* __restrict__ dec_bih, const float* __restrict__ dec_bhh,
                   const unsigned short* __restrict__ h0b,
                   float* __restrict__ enc_out, unsigned short* __restrict__ encout_bf,
                   float* __restrict__ hDf, unsigned short* __restrict__ hDb,
                   int* flags, int* gen)
{
    const int g = blockIdx.x;
    const int tid = threadIdx.x, w = tid >> 6, lane = tid & 63;
    const int l15 = lane & 15, kg = lane >> 4;
    int lgen = 0;

    if (g < 32) {
        const int cg = g >> 1, rh = g & 1;
        const int mb = rh * 64 + w * 16;
        int wrow[6];
#pragma unroll
        for (int ct = 0; ct < 6; ++ct) wrow[ct] = (ct >> 1) * 512 + cg * 32 + (ct & 1) * 16 + l15;

        for (int i = 0; i < 105; ++i) {
            const unsigned short* A = (i == 0) ? h0b : encout_bf + (size_t)(i - 1) * 65536;
            f32x4 acc[6];
#pragma unroll
            for (int ct = 0; ct < 6; ++ct) acc[ct] = f32x4{0.f, 0.f, 0.f, 0.f};
#pragma unroll 4
            for (int ks = 0; ks < 16; ++ks) {
                bf16x8 a = *(const bf16x8*)&A[(size_t)(mb + l15) * 512 + ks * 32 + kg * 8];
#pragma unroll
                for (int ct = 0; ct < 6; ++ct) {
                    bf16x8 bv = *(const bf16x8*)&encwhh_bf[(size_t)wrow[ct] * 512 + ks * 32 + kg * 8];
                    acc[ct] = __builtin_amdgcn_mfma_f32_16x16x32_bf16(a, bv, acc[ct], 0, 0, 0);
                }
            }
#pragma unroll
            for (int jh = 0; jh < 2; ++jh) {
                int jc = cg * 32 + jh * 16 + l15;
                float bhr = enc_bhh[jc], bhz = enc_bhh[512 + jc], bhn = enc_bhh[1024 + jc];
#pragma unroll
                for (int rr = 0; rr < 4; ++rr) {
                    int br = mb + kg * 4 + rr;
                    float gr_, gz_, gn_;
                    if (i < 80) {
                        const float* gp = enc_gi + ((size_t)i * 128 + br) * 1536 + jc;
                        gr_ = gp[0]; gz_ = gp[512]; gn_ = gp[1024];
                    } else {
                        gr_ = enc_bih[jc]; gz_ = enc_bih[512 + jc]; gn_ = enc_bih[1024 + jc];
                    }
                    float hp = (i == 0) ? 0.f : enc_out[(size_t)(i - 1) * 65536 + br * 512 + jc];
                    float r = sigf(gr_ + bhr + acc[jh][rr]);
                    float z = sigf(gz_ + bhz + acc[2 + jh][rr]);
                    float n = tanhf(gn_ + r * (acc[4 + jh][rr] + bhn));
                    float v = (1.f - z) * n + z * hp;
                    enc_out[(size_t)i * 65536 + br * 512 + jc] = v;
                    encout_bf[(size_t)i * 65536 + br * 512 + jc] = f2bf(v);
                }
            }
            gbar2(flags, gen, 96, ++lgen);
        }
    } else {
        const int gl = g - 32, cg = gl >> 2, rq = gl & 3;
        const int rt = w >> 1, cs = w & 1;
        const int mb = rq * 32 + rt * 16;
        int wrow[3];
#pragma unroll
        for (int t = 0; t < 3; ++t) wrow[t] = t * 512 + cg * 32 + cs * 16 + l15;
        const int jc = cg * 32 + cs * 16 + l15;

        for (int i = 0; i < 105; ++i) {
            if (i >= 1 && i <= 80) {
                f32x4 agi[3], agh[3];
#pragma unroll
                for (int t = 0; t < 3; ++t) { agi[t] = f32x4{0.f,0.f,0.f,0.f}; agh[t] = f32x4{0.f,0.f,0.f,0.f}; }
                const unsigned short* A1 = encout_bf + (size_t)(i - 1) * 65536;
#pragma unroll 4
                for (int ks = 0; ks < 16; ++ks) {
                    bf16x8 a = *(const bf16x8*)&A1[(size_t)(mb + l15) * 512 + ks * 32 + kg * 8];
#pragma unroll
                    for (int t = 0; t < 3; ++t) {
                        bf16x8 bv = *(const bf16x8*)&decwih_bf[(size_t)wrow[t] * 1536 + 1024 + ks * 32 + kg * 8];
                        agi[t] = __builtin_amdgcn_mfma_f32_16x16x32_bf16(a, bv, agi[t], 0, 0, 0);
                    }
                }
                const unsigned short* A2 = (i == 1) ? h0b : hDb + (size_t)((i - 1) & 1) * 65536;
#pragma unroll 4
                for (int ks = 0; ks < 16; ++ks) {
                    bf16x8 a = *(const bf16x8*)&A2[(size_t)(mb + l15) * 512 + ks * 32 + kg * 8];
#pragma unroll
                    for (int t = 0; t < 3; ++t) {
                        bf16x8 bv = *(const bf16x8*)&decwhh_bf[(size_t)wrow[t] * 512 + ks * 32 + kg * 8];
                        agh[t] = __builtin_amdgcn_mfma_f32_16x16x32_bf16(a, bv, agh[t], 0, 0, 0);
                    }
                }
                float bir = dec_bih[jc], bhr = dec_bhh[jc];
                float biz = dec_bih[512 + jc], bhz = dec_bhh[512 + jc];
                float bin_ = dec_bih[1024 + jc], bhn = dec_bhh[1024 + jc];
                const float* hpf = hDf + (size_t)((i - 1) & 1) * 65536;
                float* hof = hDf + (size_t)(i & 1) * 65536;
                unsigned short* hob = hDb + (size_t)(i & 1) * 65536;
#pragma unroll
                for (int rr = 0; rr < 4; ++rr) {
                    int br = mb + kg * 4 + rr;
                    float hp = (i == 1) ? 0.f : hpf[br * 512 + jc];
                    float r = sigf(agi[0][rr] + bir + agh[0][rr] + bhr);
                    float z = sigf(agi[1][rr] + biz + agh[1][rr] + bhz);
                    float n = tanhf(agi[2][rr] + bin_ + r * (agh[2][rr] + bhn));
                    float v = (1.f - z) * n + z * hp;
                    hof[br * 512 + jc] = v;
                    hob[br * 512 + jc] = f2bf(v);
                }
            }
            gbar2(flags, gen, 96, ++lgen);
        }
    }
}

// ---------------------------------------------------------------------------
// attention for batch b: s=tanh(enc_bf . h), softmax, c -> c_bf. bf16 reads.
// ---------------------------------------------------------------------------
__device__ void attention(int b, const float* __restrict__ hvec,
                          const unsigned short* __restrict__ encb,
                          unsigned short* __restrict__ c_bf,
                          float* hsh, float* ssh)
{
    const int tid = threadIdx.x;
    hsh[tid] = hvec[(size_t)b * 512 + tid];
    hsh[256 + tid] = hvec[(size_t)b * 512 + 256 + tid];
    __syncthreads();
    const int wv = tid >> 6, lane = tid & 63;
    // hoist h fragment to registers (once, not per i)
    float hreg[8];
#pragma unroll
    for (int q = 0; q < 8; ++q) hreg[q] = hsh[lane * 8 + q];
#pragma unroll 4
    for (int i = wv; i < 80; i += 4) {
        bf16x8 v = *(const bf16x8*)&encb[(size_t)i * 65536 + b * 512 + lane * 8];
        float p = 0.f;
#pragma unroll
        for (int q = 0; q < 8; ++q) p += bf2f((unsigned short)v[q]) * hreg[q];
#pragma unroll
        for (int off = 32; off > 0; off >>= 1) p += __shfl_xor(p, off, 64);
        if (lane == 0) ssh[i] = tanhf(p);
    }
    __syncthreads();
    if (tid == 0) {
        float mx = -1e30f;
        for (int i = 0; i < 80; ++i) mx = fmaxf(mx, ssh[i]);
        float s = 0.f;
        for (int i = 0; i < 80; ++i) { float e = expf(ssh[i] - mx); ssh[i] = e; s += e; }
        ssh[80] = 1.0f / s;
    }
    __syncthreads();
    // c: thread t handles hc = 2t, 2t+1 ; deep-unrolled independent loads
    float acc0 = 0.f, acc1 = 0.f;
    const unsigned short* ebase = encb + (size_t)b * 512 + tid * 2;
#pragma unroll 10
    for (int i = 0; i < 80; ++i) {
        unsigned int u = *reinterpret_cast<const unsigned int*>(&ebase[(size_t)i * 65536]);
        float w = ssh[i];
        acc0 += w * __builtin_bit_cast(float, u << 16);
        acc1 += w * __builtin_bit_cast(float, u & 0xffff0000u);
    }
    float inv = ssh[80];
    c_bf[(size_t)b * 512 + tid * 2]     = f2bf(acc0 * inv);
    c_bf[(size_t)b * 512 + tid * 2 + 1] = f2bf(acc1 * inv);
    __syncthreads();
}

// ---------------------------------------------------------------------------
// Persistent decoder: 25 steps, 3 barriers each.
// ---------------------------------------------------------------------------
__global__ __launch_bounds__(256)
void decode_persist(const unsigned short* __restrict__ encout_bf,
                    const unsigned short* __restrict__ decwih_bf, const unsigned short* __restrict__ decwhh_bf,
                    const float* __restrict__ dec_bih, const float* __restrict__ dec_bhh,
                    const unsigned short* __restrict__ outw_bf, const float* __restrict__ out_b,
                    const float* __restrict__ embed, const int* __restrict__ tgt,
                    const float* __restrict__ hDf, const unsigned short* __restrict__ hDb,
                    float* __restrict__ hCf, unsigned short* __restrict__ hCb,
                    unsigned short* __restrict__ d_bf, unsigned short* __restrict__ c_bf,
                    float* __restrict__ logits, float* __restrict__ out,
                    int* flags, int* gen)
{
    __shared__ float hsh[512];
    __shared__ float ssh[84];
    __shared__ float rmax[256];
    __shared__ int   rarg[256];
    __shared__ float rsum[256];

    const int g = blockIdx.x;          // 0..127
    const int tid = threadIdx.x, w = tid >> 6, lane = tid & 63;
    const int l15 = lane & 15, kg = lane >> 4;
    int lgen = 0;
    float loss_acc = 0.f;

    // ---- pre-phase: attention_0 from alpha; d_0 = embed[BOS]
    attention(g, hDf, encout_bf, c_bf, hsh, ssh);
    for (int t = tid; t < 512; t += 256)
        d_bf[(size_t)g * 512 + t] = f2bf(embed[(size_t)BOS * 512 + t]);
    gbar2(flags, gen, 128, ++lgen);

    for (int j = 0; j < 25; ++j) {
        const float* h_in_f = (j == 0) ? hDf : hCf + (size_t)((j - 1) & 1) * 65536;
        const unsigned short* h_in_b = (j == 0) ? hDb : hCb + (size_t)((j - 1) & 1) * 65536;
        float* h_out_f = hCf + (size_t)(j & 1) * 65536;
        unsigned short* h_out_b = hCb + (size_t)(j & 1) * 65536;

        // ---- P1: GRU step j (WGs 0..63)
        if (g < 64) {
            const int cg = g >> 2, rq = g & 3;
            const int rt = w >> 1, cs = w & 1;
            const int mb = rq * 32 + rt * 16;
            const int jc = cg * 32 + cs * 16 + l15;
            int wrow[3];
#pragma unroll
            for (int t = 0; t < 3; ++t) wrow[t] = t * 512 + cg * 32 + cs * 16 + l15;

            f32x4 agi[3], agh[3];
#pragma unroll
            for (int t = 0; t < 3; ++t) { agi[t] = f32x4{0.f,0.f,0.f,0.f}; agh[t] = f32x4{0.f,0.f,0.f,0.f}; }

            const unsigned short* segA[3] = { d_bf, encout_bf + (size_t)(80 + j) * 65536, c_bf };
#pragma unroll
            for (int s = 0; s < 3; ++s) {
                const unsigned short* A = segA[s];
                const int kofs = s * 512;
#pragma unroll 4
                for (int ks = 0; ks < 16; ++ks) {
                    bf16x8 a = *(const bf16x8*)&A[(size_t)(mb + l15) * 512 + ks * 32 + kg * 8];
#pragma unroll
                    for (int t = 0; t < 3; ++t) {
                        bf16x8 bv = *(const bf16x8*)&decwih_bf[(size_t)wrow[t] * 1536 + kofs + ks * 32 + kg * 8];
                        agi[t] = __builtin_amdgcn_mfma_f32_16x16x32_bf16(a, bv, agi[t], 0, 0, 0);
                    }
                }
            }
#pragma unroll 4
            for (int ks = 0; ks < 16; ++ks) {
                bf16x8 a = *(const bf16x8*)&h_in_b[(size_t)(mb + l15) * 512 + ks * 32 + kg * 8];
#pragma unroll
                for (int t = 0; t < 3; ++t) {
                    bf16x8 bv = *(const bf16x8*)&decwhh_bf[(size_t)wrow[t] * 512 + ks * 32 + kg * 8];
                    agh[t] = __builtin_amdgcn_mfma_f32_16x16x32_bf16(a, bv, agh[t], 0, 0, 0);
                }
            }
            float bir = dec_bih[jc], bhr = dec_bhh[jc];
            float biz = dec_bih[512 + jc], bhz = dec_bhh[512 + jc];
            float bin_ = dec_bih[1024 + jc], bhn = dec_bhh[1024 + jc];
#pragma unroll
            for (int rr = 0; rr < 4; ++rr) {
                int br = mb + kg * 4 + rr;
                float hp = h_in_f[(size_t)br * 512 + jc];
                float r = sigf(agi[0][rr] + bir + agh[0][rr] + bhr);
                float z = sigf(agi[1][rr] + biz + agh[1][rr] + bhz);
                float n = tanhf(agi[2][rr] + bin_ + r * (agh[2][rr] + bhn));
                float v = (1.f - z) * n + z * hp;
                h_out_f[(size_t)br * 512 + jc] = v;
                h_out_b[(size_t)br * 512 + jc] = f2bf(v);
            }
        }
        gbar2(flags, gen, 128, ++lgen);

        // ---- P2: logits_j (all WGs) + attention_{j+1}
        {
            const int n0 = g * 32;
            f32x4 acc[2][2];
#pragma unroll
            for (int mt = 0; mt < 2; ++mt)
#pragma unroll
                for (int nt = 0; nt < 2; ++nt) acc[mt][nt] = f32x4{0.f,0.f,0.f,0.f};
#pragma unroll 4
            for (int ks = 0; ks < 16; ++ks) {
                bf16x8 a0 = *(const bf16x8*)&h_out_b[(size_t)(w * 32 + l15) * 512 + ks * 32 + kg * 8];
                bf16x8 a1 = *(const bf16x8*)&h_out_b[(size_t)(w * 32 + 16 + l15) * 512 + ks * 32 + kg * 8];
                bf16x8 b0 = *(const bf16x8*)&outw_bf[(size_t)(n0 + l15) * 512 + ks * 32 + kg * 8];
                bf16x8 b1 = *(const bf16x8*)&outw_bf[(size_t)(n0 + 16 + l15) * 512 + ks * 32 + kg * 8];
                acc[0][0] = __builtin_amdgcn_mfma_f32_16x16x32_bf16(a0, b0, acc[0][0], 0, 0, 0);
                acc[0][1] = __builtin_amdgcn_mfma_f32_16x16x32_bf16(a0, b1, acc[0][1], 0, 0, 0);
                acc[1][0] = __builtin_amdgcn_mfma_f32_16x16x32_bf16(a1, b0, acc[1][0], 0, 0, 0);
                acc[1][1] = __builtin_amdgcn_mfma_f32_16x16x32_bf16(a1, b1, acc[1][1], 0, 0, 0);
            }
#pragma unroll
            for (int mt = 0; mt < 2; ++mt)
#pragma unroll
                for (int nt = 0; nt < 2; ++nt) {
                    int n = n0 + nt * 16 + l15;
                    float bv = out_b[n];
#pragma unroll
                    for (int rr = 0; rr < 4; ++rr) {
                        int m = w * 32 + mt * 16 + kg * 4 + rr;
                        logits[(size_t)m * 4096 + n] = acc[mt][nt][rr] + bv;
                    }
                }
            if (j < 24) attention(g, h_out_f, encout_bf, c_bf, hsh, ssh);
        }
        gbar2(flags, gen, 128, ++lgen);

        // ---- P3: loss_j + argmax feedback (WG g handles batch b=g)
        {
            const int b = g;
            const float* lg = logits + (size_t)b * 4096;
            float lmax = -1e30f; int larg = 0;
            for (int v = tid; v < 4096; v += 256) {
                float f = lg[v];
                if (f > lmax) { lmax = f; larg = v; }
            }
            rmax[tid] = lmax; rarg[tid] = larg;
            __syncthreads();
            for (int s = 128; s > 0; s >>= 1) {
                if (tid < s) {
                    float o = rmax[tid + s]; int oi = rarg[tid + s];
                    if (o > rmax[tid] || (o == rmax[tid] && oi < rarg[tid])) { rmax[tid] = o; rarg[tid] = oi; }
                }
                __syncthreads();
            }
            float gmax = rmax[0]; int garg = rarg[0];
            float s = 0.f;
            for (int v = tid; v < 4096; v += 256) s += expf(lg[v] - gmax);
            rsum[tid] = s;
            __syncthreads();
            for (int t = 128; t > 0; t >>= 1) { if (tid < t) rsum[tid] += rsum[tid + t]; __syncthreads(); }
            if (tid == 0) {
                float lse = gmax + logf(rsum[0]);
                int tj = tgt[b * 25 + j];
                loss_acc += -(lg[tj] - lse);
            }
            for (int t = tid; t < 512; t += 256)
                d_bf[(size_t)b * 512 + t] = f2bf(embed[(size_t)garg * 512 + t]);
            __syncthreads();
        }
        gbar2(flags, gen, 128, ++lgen);
    }

    if (tid == 0) atomicAdd(out, loss_acc * (1.0f / 3200.0f));
}

// fp32 -> bf16 cast (n multiple of 1024)
__global__ void cast_f2b(const float* __restrict__ in, unsigned short* __restrict__ out, int n)
{
    int i = (blockIdx.x * 256 + threadIdx.x) * 4;
    if (i < n) {
        float4 v = *reinterpret_cast<const float4*>(&in[i]);
        out[i + 0] = f2bf(v.x); out[i + 1] = f2bf(v.y);
        out[i + 2] = f2bf(v.z); out[i + 3] = f2bf(v.w);
    }
}

// ---------------------------------------------------------------------------
extern "C" void kernel_launch(void* const* d_in, const int* in_sizes, int n_in,
                              void* d_out, int out_size, void* d_ws, size_t ws_size,
                              hipStream_t stream)
{
    const float* feats   = (const float*)d_in[0];
    const float* fc_w    = (const float*)d_in[1];
    const float* fc_b    = (const float*)d_in[2];
    const float* enc_wih = (const float*)d_in[3];
    const float* enc_whh = (const float*)d_in[4];
    const float* enc_bih = (const float*)d_in[5];
    const float* enc_bhh = (const float*)d_in[6];
    const float* dec_wih = (const float*)d_in[7];
    const float* dec_whh = (const float*)d_in[8];
    const float* dec_bih = (const float*)d_in[9];
    const float* dec_bhh = (const float*)d_in[10];
    const float* out_w   = (const float*)d_in[11];
    const float* out_b   = (const float*)d_in[12];
    const float* embed   = (const float*)d_in[13];
    const int*   tgt     = (const int*)d_in[14];

    float* ws = (float*)d_ws;
    size_t off = 0;
    auto afl = [&](size_t n) { float* r = ws + off; off += n; return r; };

    float* enc_gi            = afl(15728640);              // [80][128][1536] fp32
    float* enc_out           = afl(6881280);               // [105][128][512] fp32
    unsigned short* encout_bf = (unsigned short*)afl(3440640);
    unsigned short* xp_bf     = (unsigned short*)afl(2621440);
    unsigned short* fcw_bf    = (unsigned short*)afl(1048576);
    unsigned short* encwih_bf = (unsigned short*)afl(393216);
    unsigned short* encwhh_bf = (unsigned short*)afl(393216);
    unsigned short* decwih_bf = (unsigned short*)afl(1179648);  // full 1536x1536
    unsigned short* decwhh_bf = (unsigned short*)afl(393216);
    unsigned short* outw_bf   = (unsigned short*)afl(1048576);
    unsigned short* h0b       = (unsigned short*)afl(32768);    // zeros bf16
    float* hDf               = afl(131072);                // [2][128][512]
    unsigned short* hDb       = (unsigned short*)afl(65536);
    float* hCf               = afl(131072);
    unsigned short* hCb       = (unsigned short*)afl(65536);
    unsigned short* d_bf      = (unsigned short*)afl(32768);
    unsigned short* c_bf      = (unsigned short*)afl(32768);
    float* logits            = afl(524288);
    int*   bar               = (int*)afl(8192);            // barrier state, 32KB

    int* genR   = bar;           // cacheline 0
    int* genD   = bar + 32;      // cacheline 1
    int* flagsR = bar + 64;            // 96 * 32 ints
    int* flagsD = bar + 64 + 96 * 32;  // 128 * 32 ints

    hipMemsetAsync(h0b, 0, 65536 * sizeof(unsigned short), stream);
    hipMemsetAsync(bar, 0, 8192 * sizeof(int), stream);
    hipMemsetAsync(d_out, 0, sizeof(float), stream);

    cast_f2b<<<2048, 256, 0, stream>>>(fc_w, fcw_bf, 2097152);
    cast_f2b<<<768, 256, 0, stream>>>(enc_wih, encwih_bf, 786432);
    cast_f2b<<<768, 256, 0, stream>>>(enc_whh, encwhh_bf, 786432);
    cast_f2b<<<2304, 256, 0, stream>>>(dec_wih, decwih_bf, 2359296);
    cast_f2b<<<768, 256, 0, stream>>>(dec_whh, decwhh_bf, 786432);
    cast_f2b<<<2048, 256, 0, stream>>>(out_w, outw_bf, 2097152);

    // fc: xp_bf = leaky_relu(feats @ fc_w^T + fc_b)   M=10240 K=4096 N=512
    gemm_mfma<1, 1, 1><<<dim3(4, 80), 256, 0, stream>>>(feats, 4096, fcw_bf, 4096, fc_b, xp_bf, 512, 4096);
    // enc gi (t<80): xp @ enc_wih^T + enc_bih   M=10240 K=512 N=1536
    gemm_mfma<0, 0, 0><<<dim3(12, 80), 256, 0, stream>>>(xp_bf, 512, encwih_bf, 512, enc_bih, enc_gi, 1536, 512);

    recur_persist<<<96, 256, 0, stream>>>(enc_gi, enc_bih, enc_bhh, encwhh_bf,
                                          decwih_bf, decwhh_bf, dec_bih, dec_bhh,
                                          h0b, enc_out, encout_bf, hDf, hDb,
                                          flagsR, genR);

    decode_persist<<<128, 256, 0, stream>>>(encout_bf, decwih_bf, decwhh_bf,
                                            dec_bih, dec_bhh, outw_bf, out_b,
                                            embed, tgt, hDf, hDb, hCf, hCb,
                                            d_bf, c_bf, logits, (float*)d_out,
                                            flagsD, genD);
}

// Round 5
// 4714.859 us; speedup vs baseline: 1.7833x; 1.7004x over previous
//
#include <hip/hip_runtime.h>
#include <hip/hip_bf16.h>

#define N_IN  80
#define N_OUT 25
#define BOS   4093

typedef __attribute__((ext_vector_type(8))) short bf16x8;
typedef __attribute__((ext_vector_type(4))) float f32x4;

__device__ inline unsigned short f2bf(float f) {
    unsigned int u = __builtin_bit_cast(unsigned int, f);
    unsigned int r = (u + 0x7fffu + ((u >> 16) & 1u)) >> 16;
    return (unsigned short)r;
}
__device__ inline float bf2f(unsigned short s) {
    return __builtin_bit_cast(float, (unsigned int)s << 16);
}
__device__ inline float sigf(float x) { return 1.f / (1.f + expf(-x)); }

// ---------------------------------------------------------------------------
// Coherent (agent-scope, fence-free) data movement helpers. Relaxed atomics
// compile to sc1 loads/stores that go to the coherence point: no L2 flush,
// no stale-L2 hazard. RULE: a buffer written _coh inside a kernel must be
// read _coh inside that kernel.
// ---------------------------------------------------------------------------
__device__ __forceinline__ unsigned long long ld_u64_coh(const void* p) {
    return __hip_atomic_load((const unsigned long long*)p, __ATOMIC_RELAXED, __HIP_MEMORY_SCOPE_AGENT);
}
__device__ __forceinline__ void st_u64_coh(void* p, unsigned long long v) {
    __hip_atomic_store((unsigned long long*)p, v, __ATOMIC_RELAXED, __HIP_MEMORY_SCOPE_AGENT);
}
__device__ __forceinline__ float ld_f32_coh(const float* p) {
    unsigned int u = __hip_atomic_load((const unsigned int*)p, __ATOMIC_RELAXED, __HIP_MEMORY_SCOPE_AGENT);
    return __builtin_bit_cast(float, u);
}
__device__ __forceinline__ void st_f32_coh(float* p, float v) {
    __hip_atomic_store((unsigned int*)p, __builtin_bit_cast(unsigned int, v), __ATOMIC_RELAXED, __HIP_MEMORY_SCOPE_AGENT);
}
__device__ __forceinline__ void st_u16_coh(unsigned short* p, unsigned short v) {
    __hip_atomic_store(p, v, __ATOMIC_RELAXED, __HIP_MEMORY_SCOPE_AGENT);
}
__device__ __forceinline__ bf16x8 ld_bf8_coh(const unsigned short* p) {
    union { unsigned long long u[2]; bf16x8 v; } r;
    r.u[0] = ld_u64_coh(p);
    r.u[1] = ld_u64_coh(p + 4);
    return r.v;
}
__device__ inline unsigned long long pack_ff(float a, float b) {
    return ((unsigned long long)__builtin_bit_cast(unsigned int, b) << 32) |
           __builtin_bit_cast(unsigned int, a);
}
__device__ inline unsigned long long pack_if(int a, float b) {
    return ((unsigned long long)__builtin_bit_cast(unsigned int, b) << 32) |
           (unsigned int)a;
}

// ---------------------------------------------------------------------------
// Fence-free grid barrier. __syncthreads() drains each wave's vmcnt before
// s_barrier (compiler-guaranteed), so all prior _coh stores are globally
// visible before the flag is raised. No __threadfence -> no L2 flush.
// ---------------------------------------------------------------------------
__device__ __forceinline__ void gbar3(int* flags, int* gen, int nwg, int target)
{
    __syncthreads();
    asm volatile("" ::: "memory");
    const int g = blockIdx.x, tid = threadIdx.x;
    if (g == 0) {
        if (tid >= 1 && tid < nwg) {
            while (__hip_atomic_load(&flags[tid * 32], __ATOMIC_RELAXED, __HIP_MEMORY_SCOPE_AGENT) < target)
                __builtin_amdgcn_s_sleep(1);
        }
        __syncthreads();
        if (tid == 0)
            __hip_atomic_store(gen, target, __ATOMIC_RELAXED, __HIP_MEMORY_SCOPE_AGENT);
    } else {
        if (tid == 0) {
            __hip_atomic_store(&flags[g * 32], target, __ATOMIC_RELAXED, __HIP_MEMORY_SCOPE_AGENT);
            while (__hip_atomic_load(gen, __ATOMIC_RELAXED, __HIP_MEMORY_SCOPE_AGENT) < target)
                __builtin_amdgcn_s_sleep(1);
        }
        __syncthreads();
    }
    asm volatile("" ::: "memory");
}

// ---------------------------------------------------------------------------
// bf16 MFMA GEMM: C = act(A @ W^T + bias)
// ---------------------------------------------------------------------------
template<int AFP32, int OUT_BF, int ACT>
__global__ __launch_bounds__(256)
void gemm_mfma(const void* __restrict__ Ap, int lda,
               const unsigned short* __restrict__ W, int ldw,
               const float* __restrict__ bias,
               void* __restrict__ Cp, int ldc, int K)
{
    __shared__ short Abuf[128 * 32];
    __shared__ short Wbuf[128 * 32];
    const int tid  = threadIdx.x;
    const int lane = tid & 63;
    const int wave = tid >> 6;
    const int wr = wave >> 1, wc = wave & 1;
    const int l15 = lane & 15, kg = lane >> 4;
    const int m0 = blockIdx.y * 128, n0 = blockIdx.x * 128;

    const float* Af = (const float*)Ap;
    const unsigned short* Ab = (const unsigned short*)Ap;

    f32x4 acc[4][4];
#pragma unroll
    for (int i = 0; i < 4; ++i)
#pragma unroll
        for (int j = 0; j < 4; ++j) acc[i][j] = f32x4{0.f, 0.f, 0.f, 0.f};

    const bf16x8* Av = (const bf16x8*)Abuf;
    const bf16x8* Wv = (const bf16x8*)Wbuf;

    for (int k0 = 0; k0 < K; k0 += 32) {
#pragma unroll
        for (int cc = 0; cc < 2; ++cc) {
            int c = tid + cc * 256;
            int row = c >> 2, k8 = (c & 3) * 8;
            if (AFP32) {
                const float* src = &Af[(size_t)(m0 + row) * lda + k0 + k8];
                float4 v0 = *reinterpret_cast<const float4*>(src);
                float4 v1 = *reinterpret_cast<const float4*>(src + 4);
                bf16x8 s;
                s[0] = (short)f2bf(v0.x); s[1] = (short)f2bf(v0.y);
                s[2] = (short)f2bf(v0.z); s[3] = (short)f2bf(v0.w);
                s[4] = (short)f2bf(v1.x); s[5] = (short)f2bf(v1.y);
                s[6] = (short)f2bf(v1.z); s[7] = (short)f2bf(v1.w);
                *reinterpret_cast<bf16x8*>(&Abuf[row * 32 + k8]) = s;
            } else {
                *reinterpret_cast<bf16x8*>(&Abuf[row * 32 + k8]) =
                    *reinterpret_cast<const bf16x8*>(&Ab[(size_t)(m0 + row) * lda + k0 + k8]);
            }
            *reinterpret_cast<bf16x8*>(&Wbuf[row * 32 + k8]) =
                *reinterpret_cast<const bf16x8*>(&W[(size_t)(n0 + row) * ldw + k0 + k8]);
        }
        __syncthreads();
        bf16x8 a[4], b[4];
#pragma unroll
        for (int i = 0; i < 4; ++i) a[i] = Av[(wr * 64 + i * 16 + l15) * 4 + kg];
#pragma unroll
        for (int j = 0; j < 4; ++j) b[j] = Wv[(wc * 64 + j * 16 + l15) * 4 + kg];
#pragma unroll
        for (int i = 0; i < 4; ++i)
#pragma unroll
            for (int j = 0; j < 4; ++j)
                acc[i][j] = __builtin_amdgcn_mfma_f32_16x16x32_bf16(a[i], b[j], acc[i][j], 0, 0, 0);
        __syncthreads();
    }

    float* Cf = (float*)Cp;
    unsigned short* Cb = (unsigned short*)Cp;
#pragma unroll
    for (int i = 0; i < 4; ++i) {
#pragma unroll
        for (int j = 0; j < 4; ++j) {
            int n = n0 + wc * 64 + j * 16 + l15;
            float bv = bias[n];
#pragma unroll
            for (int r = 0; r < 4; ++r) {
                int m = m0 + wr * 64 + i * 16 + kg * 4 + r;
                float v = acc[i][j][r] + bv;
                if (ACT == 1) v = v > 0.f ? v : 0.01f * v;
                if (OUT_BF) Cb[(size_t)m * ldc + n] = f2bf(v);
                else        Cf[(size_t)m * ldc + n] = v;
            }
        }
    }
}

// ---------------------------------------------------------------------------
// Persistent recurrence: 105 iterations, 1 fence-free barrier each.
// Cross-WG buffers (encout_bf, hDb) move via _coh. Weights / gi / fp32 state
// stay plain and L2-resident.
// ---------------------------------------------------------------------------
__global__ __launch_bounds__(256)
void recur_persist(const float* __restrict__ enc_gi,
                   const float* __restrict__ enc_bih, const float* __restrict__ enc_bhh,
                   const unsigned short* __restrict__ encwhh_bf,
                   const unsigned short* __restrict__ decwih_bf,
                   const unsigned short* __restrict__ decwhh_bf,
                   const float* __restrict__ dec_bih, const float* __restrict__ dec_bhh,
                   const unsigned short* __restrict__ h0b,
                   float* __restrict__ enc_out, unsigned short* __restrict__ encout_bf,
                   float* __restrict__ hDf, unsigned short* __restrict__ hDb,
                   int* flags, int* gen)
{
    const int g = blockIdx.x;
    const int tid = threadIdx.x, w = tid >> 6, lane = tid & 63;
    const int l15 = lane & 15, kg = lane >> 4;
    int lgen = 0;

    if (g < 32) {
        const int cg = g >> 1, rh = g & 1;
        const int mb = rh * 64 + w * 16;
        int wrow[6];
#pragma unroll
        for (int ct = 0; ct < 6; ++ct) wrow[ct] = (ct >> 1) * 512 + cg * 32 + (ct & 1) * 16 + l15;

        for (int i = 0; i < 105; ++i) {
            const unsigned short* A = (i == 0) ? h0b : encout_bf + (size_t)(i - 1) * 65536;
            f32x4 acc[6];
#pragma unroll
            for (int ct = 0; ct < 6; ++ct) acc[ct] = f32x4{0.f, 0.f, 0.f, 0.f};
#pragma unroll 4
            for (int ks = 0; ks < 16; ++ks) {
                bf16x8 a = ld_bf8_coh(&A[(size_t)(mb + l15) * 512 + ks * 32 + kg * 8]);
#pragma unroll
                for (int ct = 0; ct < 6; ++ct) {
                    bf16x8 bv = *(const bf16x8*)&encwhh_bf[(size_t)wrow[ct] * 512 + ks * 32 + kg * 8];
                    acc[ct] = __builtin_amdgcn_mfma_f32_16x16x32_bf16(a, bv, acc[ct], 0, 0, 0);
                }
            }
#pragma unroll
            for (int jh = 0; jh < 2; ++jh) {
                int jc = cg * 32 + jh * 16 + l15;
                float bhr = enc_bhh[jc], bhz = enc_bhh[512 + jc], bhn = enc_bhh[1024 + jc];
#pragma unroll
                for (int rr = 0; rr < 4; ++rr) {
                    int br = mb + kg * 4 + rr;
                    float gr_, gz_, gn_;
                    if (i < 80) {
                        const float* gp = enc_gi + ((size_t)i * 128 + br) * 1536 + jc;
                        gr_ = gp[0]; gz_ = gp[512]; gn_ = gp[1024];
                    } else {
                        gr_ = enc_bih[jc]; gz_ = enc_bih[512 + jc]; gn_ = enc_bih[1024 + jc];
                    }
                    float hp = (i == 0) ? 0.f : enc_out[(size_t)(i - 1) * 65536 + br * 512 + jc];
                    float r = sigf(gr_ + bhr + acc[jh][rr]);
                    float z = sigf(gz_ + bhz + acc[2 + jh][rr]);
                    float n = tanhf(gn_ + r * (acc[4 + jh][rr] + bhn));
                    float v = (1.f - z) * n + z * hp;
                    enc_out[(size_t)i * 65536 + br * 512 + jc] = v;          // same-thread RAW, plain
                    st_u16_coh(&encout_bf[(size_t)i * 65536 + br * 512 + jc], f2bf(v));
                }
            }
            gbar3(flags, gen, 96, ++lgen);
        }
    } else {
        const int gl = g - 32, cg = gl >> 2, rq = gl & 3;
        const int rt = w >> 1, cs = w & 1;
        const int mb = rq * 32 + rt * 16;
        int wrow[3];
#pragma unroll
        for (int t = 0; t < 3; ++t) wrow[t] = t * 512 + cg * 32 + cs * 16 + l15;
        const int jc = cg * 32 + cs * 16 + l15;

        for (int i = 0; i < 105; ++i) {
            if (i >= 1 && i <= 80) {
                f32x4 agi[3], agh[3];
#pragma unroll
                for (int t = 0; t < 3; ++t) { agi[t] = f32x4{0.f,0.f,0.f,0.f}; agh[t] = f32x4{0.f,0.f,0.f,0.f}; }
                const unsigned short* A1 = encout_bf + (size_t)(i - 1) * 65536;
#pragma unroll 4
                for (int ks = 0; ks < 16; ++ks) {
                    bf16x8 a = ld_bf8_coh(&A1[(size_t)(mb + l15) * 512 + ks * 32 + kg * 8]);
#pragma unroll
                    for (int t = 0; t < 3; ++t) {
                        bf16x8 bv = *(const bf16x8*)&decwih_bf[(size_t)wrow[t] * 1536 + 1024 + ks * 32 + kg * 8];
                        agi[t] = __builtin_amdgcn_mfma_f32_16x16x32_bf16(a, bv, agi[t], 0, 0, 0);
                    }
                }
                const unsigned short* A2 = (i == 1) ? h0b : hDb + (size_t)((i - 1) & 1) * 65536;
#pragma unroll 4
                for (int ks = 0; ks < 16; ++ks) {
                    bf16x8 a = ld_bf8_coh(&A2[(size_t)(mb + l15) * 512 + ks * 32 + kg * 8]);
#pragma unroll
                    for (int t = 0; t < 3; ++t) {
                        bf16x8 bv = *(const bf16x8*)&decwhh_bf[(size_t)wrow[t] * 512 + ks * 32 + kg * 8];
                        agh[t] = __builtin_amdgcn_mfma_f32_16x16x32_bf16(a, bv, agh[t], 0, 0, 0);
                    }
                }
                float bir = dec_bih[jc], bhr = dec_bhh[jc];
                float biz = dec_bih[512 + jc], bhz = dec_bhh[512 + jc];
                float bin_ = dec_bih[1024 + jc], bhn = dec_bhh[1024 + jc];
                const float* hpf = hDf + (size_t)((i - 1) & 1) * 65536;
                float* hof = hDf + (size_t)(i & 1) * 65536;
                unsigned short* hob = hDb + (size_t)(i & 1) * 65536;
#pragma unroll
                for (int rr = 0; rr < 4; ++rr) {
                    int br = mb + kg * 4 + rr;
                    float hp = (i == 1) ? 0.f : hpf[br * 512 + jc];   // same-thread RAW, plain
                    float r = sigf(agi[0][rr] + bir + agh[0][rr] + bhr);
                    float z = sigf(agi[1][rr] + biz + agh[1][rr] + bhz);
                    float n = tanhf(agi[2][rr] + bin_ + r * (agh[2][rr] + bhn));
                    float v = (1.f - z) * n + z * hp;
                    hof[br * 512 + jc] = v;
                    st_u16_coh(&hob[br * 512 + jc], f2bf(v));
                }
            }
            gbar3(flags, gen, 96, ++lgen);
        }
    }
}

// ---------------------------------------------------------------------------
// attention for batch b: h read _coh (cross-WG within kernel); enc reads
// plain (produced by previous kernel -> L2-cacheable, stays resident).
// ---------------------------------------------------------------------------
__device__ void attention(int b, const float* __restrict__ hvec,
                          const unsigned short* __restrict__ encb,
                          unsigned short* __restrict__ c_bf,
                          float* hsh, float* ssh)
{
    const int tid = threadIdx.x;
    hsh[tid]       = ld_f32_coh(&hvec[(size_t)b * 512 + tid]);
    hsh[256 + tid] = ld_f32_coh(&hvec[(size_t)b * 512 + 256 + tid]);
    __syncthreads();
    const int wv = tid >> 6, lane = tid & 63;
    float hreg[8];
#pragma unroll
    for (int q = 0; q < 8; ++q) hreg[q] = hsh[lane * 8 + q];
#pragma unroll 4
    for (int i = wv; i < 80; i += 4) {
        bf16x8 v = *(const bf16x8*)&encb[(size_t)i * 65536 + b * 512 + lane * 8];
        float p = 0.f;
#pragma unroll
        for (int q = 0; q < 8; ++q) p += bf2f((unsigned short)v[q]) * hreg[q];
#pragma unroll
        for (int off = 32; off > 0; off >>= 1) p += __shfl_xor(p, off, 64);
        if (lane == 0) ssh[i] = tanhf(p);
    }
    __syncthreads();
    if (tid == 0) {
        float mx = -1e30f;
        for (int i = 0; i < 80; ++i) mx = fmaxf(mx, ssh[i]);
        float s = 0.f;
        for (int i = 0; i < 80; ++i) { float e = expf(ssh[i] - mx); ssh[i] = e; s += e; }
        ssh[80] = 1.0f / s;
    }
    __syncthreads();
    float acc0 = 0.f, acc1 = 0.f;
    const unsigned short* ebase = encb + (size_t)b * 512 + tid * 2;
#pragma unroll 10
    for (int i = 0; i < 80; ++i) {
        unsigned int u = *reinterpret_cast<const unsigned int*>(&ebase[(size_t)i * 65536]);
        float w = ssh[i];
        acc0 += w * __builtin_bit_cast(float, u << 16);
        acc1 += w * __builtin_bit_cast(float, u & 0xffff0000u);
    }
    float inv = ssh[80];
    st_u16_coh(&c_bf[(size_t)b * 512 + tid * 2],     f2bf(acc0 * inv));
    st_u16_coh(&c_bf[(size_t)b * 512 + tid * 2 + 1], f2bf(acc1 * inv));
    __syncthreads();
}

// ---------------------------------------------------------------------------
// Persistent decoder: 25 steps x 3 phases. Logits are never materialized:
// P2 produces per-WG softmax partials (max, idx, sumexp, tgt-logit) which P3
// combines.
// ---------------------------------------------------------------------------
__global__ __launch_bounds__(256)
void decode_persist(const unsigned short* __restrict__ encout_bf,
                    const unsigned short* __restrict__ decwih_bf, const unsigned short* __restrict__ decwhh_bf,
                    const float* __restrict__ dec_bih, const float* __restrict__ dec_bhh,
                    const unsigned short* __restrict__ outw_bf, const float* __restrict__ out_b,
                    const float* __restrict__ embed, const int* __restrict__ tgt,
                    const float* __restrict__ hDf, const unsigned short* __restrict__ hDb,
                    float* __restrict__ hCf, unsigned short* __restrict__ hCb,
                    unsigned short* __restrict__ d_bf, unsigned short* __restrict__ c_bf,
                    unsigned long long* __restrict__ pA, unsigned long long* __restrict__ pB,
                    float* __restrict__ out,
                    int* flags, int* gen)
{
    __shared__ float hsh[512];
    __shared__ float ssh[88];
    __shared__ float sM[128];
    __shared__ int   sI[128];
    __shared__ float sL[128];

    const int g = blockIdx.x;          // 0..127
    const int tid = threadIdx.x, w = tid >> 6, lane = tid & 63;
    const int l15 = lane & 15, kg = lane >> 4;
    int lgen = 0;
    float loss_acc = 0.f;

    // ---- pre-phase: attention_0 from alpha; d_0 = embed[BOS]
    attention(g, hDf, encout_bf, c_bf, hsh, ssh);
    for (int t = tid; t < 512; t += 256)
        st_u16_coh(&d_bf[(size_t)g * 512 + t], f2bf(embed[(size_t)BOS * 512 + t]));
    gbar3(flags, gen, 128, ++lgen);

    for (int j = 0; j < 25; ++j) {
        const float* h_in_f = (j == 0) ? hDf : hCf + (size_t)((j - 1) & 1) * 65536;
        const unsigned short* h_in_b = (j == 0) ? hDb : hCb + (size_t)((j - 1) & 1) * 65536;
        float* h_out_f = hCf + (size_t)(j & 1) * 65536;
        unsigned short* h_out_b = hCb + (size_t)(j & 1) * 65536;

        // ---- P1: GRU step j (WGs 0..63)
        if (g < 64) {
            const int cg = g >> 2, rq = g & 3;
            const int rt = w >> 1, cs = w & 1;
            const int mb = rq * 32 + rt * 16;
            const int jc = cg * 32 + cs * 16 + l15;
            int wrow[3];
#pragma unroll
            for (int t = 0; t < 3; ++t) wrow[t] = t * 512 + cg * 32 + cs * 16 + l15;

            f32x4 agi[3], agh[3];
#pragma unroll
            for (int t = 0; t < 3; ++t) { agi[t] = f32x4{0.f,0.f,0.f,0.f}; agh[t] = f32x4{0.f,0.f,0.f,0.f}; }

            // seg 0: d (coh)
#pragma unroll 4
            for (int ks = 0; ks < 16; ++ks) {
                bf16x8 a = ld_bf8_coh(&d_bf[(size_t)(mb + l15) * 512 + ks * 32 + kg * 8]);
#pragma unroll
                for (int t = 0; t < 3; ++t) {
                    bf16x8 bv = *(const bf16x8*)&decwih_bf[(size_t)wrow[t] * 1536 + 0 + ks * 32 + kg * 8];
                    agi[t] = __builtin_amdgcn_mfma_f32_16x16x32_bf16(a, bv, agi[t], 0, 0, 0);
                }
            }
            // seg 1: enc tail (plain, inter-kernel)
            const unsigned short* et = encout_bf + (size_t)(80 + j) * 65536;
#pragma unroll 4
            for (int ks = 0; ks < 16; ++ks) {
                bf16x8 a = *(const bf16x8*)&et[(size_t)(mb + l15) * 512 + ks * 32 + kg * 8];
#pragma unroll
                for (int t = 0; t < 3; ++t) {
                    bf16x8 bv = *(const bf16x8*)&decwih_bf[(size_t)wrow[t] * 1536 + 512 + ks * 32 + kg * 8];
                    agi[t] = __builtin_amdgcn_mfma_f32_16x16x32_bf16(a, bv, agi[t], 0, 0, 0);
                }
            }
            // seg 2: context c (coh)
#pragma unroll 4
            for (int ks = 0; ks < 16; ++ks) {
                bf16x8 a = ld_bf8_coh(&c_bf[(size_t)(mb + l15) * 512 + ks * 32 + kg * 8]);
#pragma unroll
                for (int t = 0; t < 3; ++t) {
                    bf16x8 bv = *(const bf16x8*)&decwih_bf[(size_t)wrow[t] * 1536 + 1024 + ks * 32 + kg * 8];
                    agi[t] = __builtin_amdgcn_mfma_f32_16x16x32_bf16(a, bv, agi[t], 0, 0, 0);
                }
            }
            // gh: h_in (coh)
#pragma unroll 4
            for (int ks = 0; ks < 16; ++ks) {
                bf16x8 a = ld_bf8_coh(&h_in_b[(size_t)(mb + l15) * 512 + ks * 32 + kg * 8]);
#pragma unroll
                for (int t = 0; t < 3; ++t) {
                    bf16x8 bv = *(const bf16x8*)&decwhh_bf[(size_t)wrow[t] * 512 + ks * 32 + kg * 8];
                    agh[t] = __builtin_amdgcn_mfma_f32_16x16x32_bf16(a, bv, agh[t], 0, 0, 0);
                }
            }
            float bir = dec_bih[jc], bhr = dec_bhh[jc];
            float biz = dec_bih[512 + jc], bhz = dec_bhh[512 + jc];
            float bin_ = dec_bih[1024 + jc], bhn = dec_bhh[1024 + jc];
#pragma unroll
            for (int rr = 0; rr < 4; ++rr) {
                int br = mb + kg * 4 + rr;
                float hp = ld_f32_coh(&h_in_f[(size_t)br * 512 + jc]);
                float r = sigf(agi[0][rr] + bir + agh[0][rr] + bhr);
                float z = sigf(agi[1][rr] + biz + agh[1][rr] + bhz);
                float n = tanhf(agi[2][rr] + bin_ + r * (agh[2][rr] + bhn));
                float v = (1.f - z) * n + z * hp;
                st_f32_coh(&h_out_f[(size_t)br * 512 + jc], v);
                st_u16_coh(&h_out_b[(size_t)br * 512 + jc], f2bf(v));
            }
        }
        gbar3(flags, gen, 128, ++lgen);

        // ---- P2: logits slice (all WGs; cols n0..n0+31) -> softmax partials;
        //          then attention_{j+1}
        {
            const int n0 = g * 32;
            f32x4 acc[2][2];
#pragma unroll
            for (int mt = 0; mt < 2; ++mt)
#pragma unroll
                for (int nt = 0; nt < 2; ++nt) acc[mt][nt] = f32x4{0.f,0.f,0.f,0.f};
#pragma unroll 4
            for (int ks = 0; ks < 16; ++ks) {
                bf16x8 a0 = ld_bf8_coh(&h_out_b[(size_t)(w * 32 + l15) * 512 + ks * 32 + kg * 8]);
                bf16x8 a1 = ld_bf8_coh(&h_out_b[(size_t)(w * 32 + 16 + l15) * 512 + ks * 32 + kg * 8]);
                bf16x8 b0 = *(const bf16x8*)&outw_bf[(size_t)(n0 + l15) * 512 + ks * 32 + kg * 8];
                bf16x8 b1 = *(const bf16x8*)&outw_bf[(size_t)(n0 + 16 + l15) * 512 + ks * 32 + kg * 8];
                acc[0][0] = __builtin_amdgcn_mfma_f32_16x16x32_bf16(a0, b0, acc[0][0], 0, 0, 0);
                acc[0][1] = __builtin_amdgcn_mfma_f32_16x16x32_bf16(a0, b1, acc[0][1], 0, 0, 0);
                acc[1][0] = __builtin_amdgcn_mfma_f32_16x16x32_bf16(a1, b0, acc[1][0], 0, 0, 0);
                acc[1][1] = __builtin_amdgcn_mfma_f32_16x16x32_bf16(a1, b1, acc[1][1], 0, 0, 0);
            }
            float ob0 = out_b[n0 + l15], ob1 = out_b[n0 + 16 + l15];
#pragma unroll
            for (int mt = 0; mt < 2; ++mt) {
#pragma unroll
                for (int rr = 0; rr < 4; ++rr) {
                    int m = w * 32 + mt * 16 + kg * 4 + rr;     // batch row
                    float v0 = acc[mt][0][rr] + ob0;            // col n0+l15
                    float v1 = acc[mt][1][rr] + ob1;            // col n0+16+l15
                    int tj = tgt[m * 25 + j];
                    // per-thread partials over its 2 cols
                    float pm; int pi;
                    if (v0 >= v1) { pm = v0; pi = n0 + l15; }
                    else          { pm = v1; pi = n0 + 16 + l15; }
                    float pl = -1e30f;
                    if (n0 + l15 == tj)      pl = v0;
                    if (n0 + 16 + l15 == tj) pl = v1;
                    // 16-lane butterfly (stays within l15 group)
#pragma unroll
                    for (int off = 1; off < 16; off <<= 1) {
                        float om = __shfl_xor(pm, off, 64);
                        int   oi = __shfl_xor(pi, off, 64);
                        float ol = __shfl_xor(pl, off, 64);
                        if (om > pm || (om == pm && oi < pi)) { pm = om; pi = oi; }
                        pl = fmaxf(pl, ol);
                    }
                    float ps = expf(v0 - pm) + expf(v1 - pm);
#pragma unroll
                    for (int off = 1; off < 16; off <<= 1) ps += __shfl_xor(ps, off, 64);
                    if (l15 == 0) {
                        st_u64_coh(&pA[(size_t)m * 128 + g], pack_ff(pm, ps));
                        st_u64_coh(&pB[(size_t)m * 128 + g], pack_if(pi, pl));
                    }
                }
            }
            if (j < 24) attention(g, h_out_f, encout_bf, c_bf, hsh, ssh);
        }
        gbar3(flags, gen, 128, ++lgen);

        // ---- P3: combine partials for batch b=g; loss + argmax feedback
        {
            const int b = g;
            float m_ = -1e30f, s_ = 0.f, l_ = -1e30f; int i_ = 0x7fffffff;
            if (tid < 128) {
                unsigned long long ua = ld_u64_coh(&pA[(size_t)b * 128 + tid]);
                unsigned long long ub = ld_u64_coh(&pB[(size_t)b * 128 + tid]);
                m_ = __builtin_bit_cast(float, (unsigned int)ua);
                s_ = __builtin_bit_cast(float, (unsigned int)(ua >> 32));
                i_ = (int)(unsigned int)ub;
                l_ = __builtin_bit_cast(float, (unsigned int)(ub >> 32));
            }
            if (tid < 128) { sM[tid] = m_; sI[tid] = i_; sL[tid] = l_; }
            __syncthreads();
            for (int s = 64; s > 0; s >>= 1) {
                if (tid < s) {
                    float om = sM[tid + s]; int oi = sI[tid + s];
                    if (om > sM[tid] || (om == sM[tid] && oi < sI[tid])) { sM[tid] = om; sI[tid] = oi; }
                    sL[tid] = fmaxf(sL[tid], sL[tid + s]);
                }
                __syncthreads();
            }
            float M = sM[0]; float LT = sL[0];
            if (tid == 0) { ssh[82] = M; }
            __syncthreads();
            int gidx = sI[0];
            __syncthreads();
            if (tid < 128) sM[tid] = s_ * expf(m_ - M);
            __syncthreads();
            for (int s = 64; s > 0; s >>= 1) {
                if (tid < s) sM[tid] += sM[tid + s];
                __syncthreads();
            }
            if (tid == 0) {
                float lse = M + logf(sM[0]);
                loss_acc += -(LT - lse);
            }
            for (int t = tid; t < 512; t += 256)
                st_u16_coh(&d_bf[(size_t)b * 512 + t], f2bf(embed[(size_t)gidx * 512 + t]));
            __syncthreads();
        }
        gbar3(flags, gen, 128, ++lgen);
    }

    if (tid == 0) atomicAdd(out, loss_acc * (1.0f / 3200.0f));
}

// fp32 -> bf16 cast (n multiple of 1024)
__global__ void cast_f2b(const float* __restrict__ in, unsigned short* __restrict__ out, int n)
{
    int i = (blockIdx.x * 256 + threadIdx.x) * 4;
    if (i < n) {
        float4 v = *reinterpret_cast<const float4*>(&in[i]);
        out[i + 0] = f2bf(v.x); out[i + 1] = f2bf(v.y);
        out[i + 2] = f2bf(v.z); out[i + 3] = f2bf(v.w);
    }
}

// ---------------------------------------------------------------------------
extern "C" void kernel_launch(void* const* d_in, const int* in_sizes, int n_in,
                              void* d_out, int out_size, void* d_ws, size_t ws_size,
                              hipStream_t stream)
{
    const float* feats   = (const float*)d_in[0];
    const float* fc_w    = (const float*)d_in[1];
    const float* fc_b    = (const float*)d_in[2];
    const float* enc_wih = (const float*)d_in[3];
    const float* enc_whh = (const float*)d_in[4];
    const float* enc_bih = (const float*)d_in[5];
    const float* enc_bhh = (const float*)d_in[6];
    const float* dec_wih = (const float*)d_in[7];
    const float* dec_whh = (const float*)d_in[8];
    const float* dec_bih = (const float*)d_in[9];
    const float* dec_bhh = (const float*)d_in[10];
    const float* out_w   = (const float*)d_in[11];
    const float* out_b   = (const float*)d_in[12];
    const float* embed   = (const float*)d_in[13];
    const int*   tgt     = (const int*)d_in[14];

    float* ws = (float*)d_ws;
    size_t off = 0;
    auto afl = [&](size_t n) { float* r = ws + off; off += n; return r; };

    float* enc_gi            = afl(15728640);              // [80][128][1536] fp32
    float* enc_out           = afl(6881280);               // [105][128][512] fp32
    unsigned short* encout_bf = (unsigned short*)afl(3440640);
    unsigned short* xp_bf     = (unsigned short*)afl(2621440);
    unsigned short* fcw_bf    = (unsigned short*)afl(1048576);
    unsigned short* encwih_bf = (unsigned short*)afl(393216);
    unsigned short* encwhh_bf = (unsigned short*)afl(393216);
    unsigned short* decwih_bf = (unsigned short*)afl(1179648);  // full 1536x1536
    unsigned short* decwhh_bf = (unsigned short*)afl(393216);
    unsigned short* outw_bf   = (unsigned short*)afl(1048576);
    unsigned short* h0b       = (unsigned short*)afl(32768);    // zeros bf16
    float* hDf               = afl(131072);                // [2][128][512]
    unsigned short* hDb       = (unsigned short*)afl(65536);
    float* hCf               = afl(131072);
    unsigned short* hCb       = (unsigned short*)afl(65536);
    unsigned short* d_bf      = (unsigned short*)afl(32768);
    unsigned short* c_bf      = (unsigned short*)afl(32768);
    unsigned long long* pA   = (unsigned long long*)afl(32768); // [128][128] u64
    unsigned long long* pB   = (unsigned long long*)afl(32768);
    int*   bar               = (int*)afl(8192);            // barrier state

    int* genR   = bar;
    int* genD   = bar + 32;
    int* flagsR = bar + 64;
    int* flagsD = bar + 64 + 96 * 32;

    hipMemsetAsync(h0b, 0, 65536 * sizeof(unsigned short), stream);
    hipMemsetAsync(bar, 0, 8192 * sizeof(int), stream);
    hipMemsetAsync(d_out, 0, sizeof(float), stream);

    cast_f2b<<<2048, 256, 0, stream>>>(fc_w, fcw_bf, 2097152);
    cast_f2b<<<768, 256, 0, stream>>>(enc_wih, encwih_bf, 786432);
    cast_f2b<<<768, 256, 0, stream>>>(enc_whh, encwhh_bf, 786432);
    cast_f2b<<<2304, 256, 0, stream>>>(dec_wih, decwih_bf, 2359296);
    cast_f2b<<<768, 256, 0, stream>>>(dec_whh, decwhh_bf, 786432);
    cast_f2b<<<2048, 256, 0, stream>>>(out_w, outw_bf, 2097152);

    // fc: xp_bf = leaky_relu(feats @ fc_w^T + fc_b)   M=10240 K=4096 N=512
    gemm_mfma<1, 1, 1><<<dim3(4, 80), 256, 0, stream>>>(feats, 4096, fcw_bf, 4096, fc_b, xp_bf, 512, 4096);
    // enc gi (t<80): xp @ enc_wih^T + enc_bih   M=10240 K=512 N=1536
    gemm_mfma<0, 0, 0><<<dim3(12, 80), 256, 0, stream>>>(xp_bf, 512, encwih_bf, 512, enc_bih, enc_gi, 1536, 512);

    recur_persist<<<96, 256, 0, stream>>>(enc_gi, enc_bih, enc_bhh, encwhh_bf,
                                          decwih_bf, decwhh_bf, dec_bih, dec_bhh,
                                          h0b, enc_out, encout_bf, hDf, hDb,
                                          flagsR, genR);

    decode_persist<<<128, 256, 0, stream>>>(encout_bf, decwih_bf, decwhh_bf,
                                            dec_bih, dec_bhh, outw_bf, out_b,
                                            embed, tgt, hDf, hDb, hCf, hCb,
                                            d_bf, c_bf, pA, pB, (float*)d_out,
                                            flagsD, genD);
}

// Round 6
// 4357.365 us; speedup vs baseline: 1.9296x; 1.0820x over previous
//
#include <hip/hip_runtime.h>
#include <hip/hip_bf16.h>

#define N_IN  80
#define N_OUT 25
#define BOS   4093

typedef __attribute__((ext_vector_type(8))) short bf16x8;
typedef __attribute__((ext_vector_type(4))) float f32x4;

__device__ inline unsigned short f2bf(float f) {
    unsigned int u = __builtin_bit_cast(unsigned int, f);
    unsigned int r = (u + 0x7fffu + ((u >> 16) & 1u)) >> 16;
    return (unsigned short)r;
}
__device__ inline float bf2f(unsigned short s) {
    return __builtin_bit_cast(float, (unsigned int)s << 16);
}
__device__ inline float sigf(float x) { return 1.f / (1.f + expf(-x)); }

// ---------------------------------------------------------------------------
// Coherent (agent-scope, fence-free) helpers. Relaxed atomics -> sc1 ops that
// bypass the (non-coherent) per-XCD L2 and hit the coherence point directly.
// RULE: buffers written _coh inside a kernel are read _coh inside that kernel.
// Cross-kernel handoff is safe via end-of-dispatch cache flush.
// ---------------------------------------------------------------------------
__device__ __forceinline__ unsigned long long ld_u64_coh(const void* p) {
    return __hip_atomic_load((const unsigned long long*)p, __ATOMIC_RELAXED, __HIP_MEMORY_SCOPE_AGENT);
}
__device__ __forceinline__ void st_u64_coh(void* p, unsigned long long v) {
    __hip_atomic_store((unsigned long long*)p, v, __ATOMIC_RELAXED, __HIP_MEMORY_SCOPE_AGENT);
}
__device__ __forceinline__ float ld_f32_coh(const float* p) {
    unsigned int u = __hip_atomic_load((const unsigned int*)p, __ATOMIC_RELAXED, __HIP_MEMORY_SCOPE_AGENT);
    return __builtin_bit_cast(float, u);
}
__device__ __forceinline__ void st_f32_coh(float* p, float v) {
    __hip_atomic_store((unsigned int*)p, __builtin_bit_cast(unsigned int, v), __ATOMIC_RELAXED, __HIP_MEMORY_SCOPE_AGENT);
}
__device__ __forceinline__ void st_u16_coh(unsigned short* p, unsigned short v) {
    __hip_atomic_store(p, v, __ATOMIC_RELAXED, __HIP_MEMORY_SCOPE_AGENT);
}
__device__ __forceinline__ bf16x8 ld_bf8_coh(const unsigned short* p) {
    union { unsigned long long u[2]; bf16x8 v; } r;
    r.u[0] = ld_u64_coh(p);
    r.u[1] = ld_u64_coh(p + 4);
    return r.v;
}
__device__ inline unsigned long long pack_ff(float a, float b) {
    return ((unsigned long long)__builtin_bit_cast(unsigned int, b) << 32) |
           __builtin_bit_cast(unsigned int, a);
}
__device__ inline unsigned long long pack_if(int a, float b) {
    return ((unsigned long long)__builtin_bit_cast(unsigned int, b) << 32) |
           (unsigned int)a;
}

// ---------------------------------------------------------------------------
// Distributed fence-free grid barrier: every WG raises its own flag line;
// thread t of every WG polls flag t. One visibility propagation, no central
// gather/publish round trip. __syncthreads() drains vmcnt first, so all prior
// sc1 stores are globally visible before the flag is raised.
// ---------------------------------------------------------------------------
__device__ __forceinline__ void gbar4(int* flags, int nwg, int target)
{
    __syncthreads();
    asm volatile("" ::: "memory");
    const int tid = threadIdx.x;
    if (tid == 0)
        __hip_atomic_store(&flags[blockIdx.x * 32], target, __ATOMIC_RELAXED, __HIP_MEMORY_SCOPE_AGENT);
    if (tid < nwg) {
        while (__hip_atomic_load(&flags[tid * 32], __ATOMIC_RELAXED, __HIP_MEMORY_SCOPE_AGENT) < target)
            __builtin_amdgcn_s_sleep(1);
    }
    __syncthreads();
    asm volatile("" ::: "memory");
}

// ---------------------------------------------------------------------------
// bf16 MFMA GEMM: C = act(A @ W^T + bias)
// ---------------------------------------------------------------------------
template<int AFP32, int OUT_BF, int ACT>
__global__ __launch_bounds__(256)
void gemm_mfma(const void* __restrict__ Ap, int lda,
               const unsigned short* __restrict__ W, int ldw,
               const float* __restrict__ bias,
               void* __restrict__ Cp, int ldc, int K)
{
    __shared__ short Abuf[128 * 32];
    __shared__ short Wbuf[128 * 32];
    const int tid  = threadIdx.x;
    const int lane = tid & 63;
    const int wave = tid >> 6;
    const int wr = wave >> 1, wc = wave & 1;
    const int l15 = lane & 15, kg = lane >> 4;
    const int m0 = blockIdx.y * 128, n0 = blockIdx.x * 128;

    const float* Af = (const float*)Ap;
    const unsigned short* Ab = (const unsigned short*)Ap;

    f32x4 acc[4][4];
#pragma unroll
    for (int i = 0; i < 4; ++i)
#pragma unroll
        for (int j = 0; j < 4; ++j) acc[i][j] = f32x4{0.f, 0.f, 0.f, 0.f};

    const bf16x8* Av = (const bf16x8*)Abuf;
    const bf16x8* Wv = (const bf16x8*)Wbuf;

    for (int k0 = 0; k0 < K; k0 += 32) {
#pragma unroll
        for (int cc = 0; cc < 2; ++cc) {
            int c = tid + cc * 256;
            int row = c >> 2, k8 = (c & 3) * 8;
            if (AFP32) {
                const float* src = &Af[(size_t)(m0 + row) * lda + k0 + k8];
                float4 v0 = *reinterpret_cast<const float4*>(src);
                float4 v1 = *reinterpret_cast<const float4*>(src + 4);
                bf16x8 s;
                s[0] = (short)f2bf(v0.x); s[1] = (short)f2bf(v0.y);
                s[2] = (short)f2bf(v0.z); s[3] = (short)f2bf(v0.w);
                s[4] = (short)f2bf(v1.x); s[5] = (short)f2bf(v1.y);
                s[6] = (short)f2bf(v1.z); s[7] = (short)f2bf(v1.w);
                *reinterpret_cast<bf16x8*>(&Abuf[row * 32 + k8]) = s;
            } else {
                *reinterpret_cast<bf16x8*>(&Abuf[row * 32 + k8]) =
                    *reinterpret_cast<const bf16x8*>(&Ab[(size_t)(m0 + row) * lda + k0 + k8]);
            }
            *reinterpret_cast<bf16x8*>(&Wbuf[row * 32 + k8]) =
                *reinterpret_cast<const bf16x8*>(&W[(size_t)(n0 + row) * ldw + k0 + k8]);
        }
        __syncthreads();
        bf16x8 a[4], b[4];
#pragma unroll
        for (int i = 0; i < 4; ++i) a[i] = Av[(wr * 64 + i * 16 + l15) * 4 + kg];
#pragma unroll
        for (int j = 0; j < 4; ++j) b[j] = Wv[(wc * 64 + j * 16 + l15) * 4 + kg];
#pragma unroll
        for (int i = 0; i < 4; ++i)
#pragma unroll
            for (int j = 0; j < 4; ++j)
                acc[i][j] = __builtin_amdgcn_mfma_f32_16x16x32_bf16(a[i], b[j], acc[i][j], 0, 0, 0);
        __syncthreads();
    }

    float* Cf = (float*)Cp;
    unsigned short* Cb = (unsigned short*)Cp;
#pragma unroll
    for (int i = 0; i < 4; ++i) {
#pragma unroll
        for (int j = 0; j < 4; ++j) {
            int n = n0 + wc * 64 + j * 16 + l15;
            float bv = bias[n];
#pragma unroll
            for (int r = 0; r < 4; ++r) {
                int m = m0 + wr * 64 + i * 16 + kg * 4 + r;
                float v = acc[i][j][r] + bv;
                if (ACT == 1) v = v > 0.f ? v : 0.01f * v;
                if (OUT_BF) Cb[(size_t)m * ldc + n] = f2bf(v);
                else        Cf[(size_t)m * ldc + n] = v;
            }
        }
    }
}

// ---------------------------------------------------------------------------
// Persistent recurrence: 105 iterations, 1 barrier each.
// All coherent A-fragment loads are BATCHED into registers (issued back-to-
// back, all in flight) before the MFMA loop.
// ---------------------------------------------------------------------------
__global__ __launch_bounds__(256, 1)
void recur_persist(const float* __restrict__ enc_gi,
                   const float* __restrict__ enc_bih, const float* __restrict__ enc_bhh,
                   const unsigned short* __restrict__ encwhh_bf,
                   const unsigned short* __restrict__ decwih_bf,
                   const unsigned short* __restrict__ decwhh_bf,
                   const float* __restrict__ dec_bih, const float* __restrict__ dec_bhh,
                   const unsigned short* __restrict__ h0b,
                   float* __restrict__ enc_out, unsigned short* __restrict__ encout_bf,
                   float* __restrict__ hDf, unsigned short* __restrict__ hDb,
                   int* flags)
{
    const int g = blockIdx.x;
    const int tid = threadIdx.x, w = tid >> 6, lane = tid & 63;
    const int l15 = lane & 15, kg = lane >> 4;
    int lgen = 0;

    if (g < 32) {
        const int cg = g >> 1, rh = g & 1;
        const int mb = rh * 64 + w * 16;
        int wrow[6];
#pragma unroll
        for (int ct = 0; ct < 6; ++ct) wrow[ct] = (ct >> 1) * 512 + cg * 32 + (ct & 1) * 16 + l15;

        for (int i = 0; i < 105; ++i) {
            const unsigned short* A = (i == 0) ? h0b : encout_bf + (size_t)(i - 1) * 65536;
            bf16x8 areg[16];
#pragma unroll
            for (int ks = 0; ks < 16; ++ks)
                areg[ks] = ld_bf8_coh(&A[(size_t)(mb + l15) * 512 + ks * 32 + kg * 8]);
            f32x4 acc[6];
#pragma unroll
            for (int ct = 0; ct < 6; ++ct) acc[ct] = f32x4{0.f, 0.f, 0.f, 0.f};
#pragma unroll
            for (int ks = 0; ks < 16; ++ks) {
#pragma unroll
                for (int ct = 0; ct < 6; ++ct) {
                    bf16x8 bv = *(const bf16x8*)&encwhh_bf[(size_t)wrow[ct] * 512 + ks * 32 + kg * 8];
                    acc[ct] = __builtin_amdgcn_mfma_f32_16x16x32_bf16(areg[ks], bv, acc[ct], 0, 0, 0);
                }
            }
#pragma unroll
            for (int jh = 0; jh < 2; ++jh) {
                int jc = cg * 32 + jh * 16 + l15;
                float bhr = enc_bhh[jc], bhz = enc_bhh[512 + jc], bhn = enc_bhh[1024 + jc];
#pragma unroll
                for (int rr = 0; rr < 4; ++rr) {
                    int br = mb + kg * 4 + rr;
                    float gr_, gz_, gn_;
                    if (i < 80) {
                        const float* gp = enc_gi + ((size_t)i * 128 + br) * 1536 + jc;
                        gr_ = gp[0]; gz_ = gp[512]; gn_ = gp[1024];
                    } else {
                        gr_ = enc_bih[jc]; gz_ = enc_bih[512 + jc]; gn_ = enc_bih[1024 + jc];
                    }
                    float hp = (i == 0) ? 0.f : enc_out[(size_t)(i - 1) * 65536 + br * 512 + jc];
                    float r = sigf(gr_ + bhr + acc[jh][rr]);
                    float z = sigf(gz_ + bhz + acc[2 + jh][rr]);
                    float n = tanhf(gn_ + r * (acc[4 + jh][rr] + bhn));
                    float v = (1.f - z) * n + z * hp;
                    enc_out[(size_t)i * 65536 + br * 512 + jc] = v;          // same-thread RAW
                    st_u16_coh(&encout_bf[(size_t)i * 65536 + br * 512 + jc], f2bf(v));
                }
            }
            gbar4(flags, 96, ++lgen);
        }
    } else {
        const int gl = g - 32, cg = gl >> 2, rq = gl & 3;
        const int rt = w >> 1, cs = w & 1;
        const int mb = rq * 32 + rt * 16;
        int wrow[3];
#pragma unroll
        for (int t = 0; t < 3; ++t) wrow[t] = t * 512 + cg * 32 + cs * 16 + l15;
        const int jc = cg * 32 + cs * 16 + l15;

        for (int i = 0; i < 105; ++i) {
            if (i >= 1 && i <= 80) {
                f32x4 agi[3], agh[3];
#pragma unroll
                for (int t = 0; t < 3; ++t) { agi[t] = f32x4{0.f,0.f,0.f,0.f}; agh[t] = f32x4{0.f,0.f,0.f,0.f}; }
                bf16x8 areg[16];
                const unsigned short* A1 = encout_bf + (size_t)(i - 1) * 65536;
#pragma unroll
                for (int ks = 0; ks < 16; ++ks)
                    areg[ks] = ld_bf8_coh(&A1[(size_t)(mb + l15) * 512 + ks * 32 + kg * 8]);
#pragma unroll
                for (int ks = 0; ks < 16; ++ks) {
#pragma unroll
                    for (int t = 0; t < 3; ++t) {
                        bf16x8 bv = *(const bf16x8*)&decwih_bf[(size_t)wrow[t] * 1536 + 1024 + ks * 32 + kg * 8];
                        agi[t] = __builtin_amdgcn_mfma_f32_16x16x32_bf16(areg[ks], bv, agi[t], 0, 0, 0);
                    }
                }
                const unsigned short* A2 = (i == 1) ? h0b : hDb + (size_t)((i - 1) & 1) * 65536;
#pragma unroll
                for (int ks = 0; ks < 16; ++ks)
                    areg[ks] = ld_bf8_coh(&A2[(size_t)(mb + l15) * 512 + ks * 32 + kg * 8]);
#pragma unroll
                for (int ks = 0; ks < 16; ++ks) {
#pragma unroll
                    for (int t = 0; t < 3; ++t) {
                        bf16x8 bv = *(const bf16x8*)&decwhh_bf[(size_t)wrow[t] * 512 + ks * 32 + kg * 8];
                        agh[t] = __builtin_amdgcn_mfma_f32_16x16x32_bf16(areg[ks], bv, agh[t], 0, 0, 0);
                    }
                }
                float bir = dec_bih[jc], bhr = dec_bhh[jc];
                float biz = dec_bih[512 + jc], bhz = dec_bhh[512 + jc];
                float bin_ = dec_bih[1024 + jc], bhn = dec_bhh[1024 + jc];
                const float* hpf = hDf + (size_t)((i - 1) & 1) * 65536;
                float* hof = hDf + (size_t)(i & 1) * 65536;
                unsigned short* hob = hDb + (size_t)(i & 1) * 65536;
#pragma unroll
                for (int rr = 0; rr < 4; ++rr) {
                    int br = mb + kg * 4 + rr;
                    float hp = (i == 1) ? 0.f : hpf[br * 512 + jc];   // same-thread RAW
                    float r = sigf(agi[0][rr] + bir + agh[0][rr] + bhr);
                    float z = sigf(agi[1][rr] + biz + agh[1][rr] + bhz);
                    float n = tanhf(agi[2][rr] + bin_ + r * (agh[2][rr] + bhn));
                    float v = (1.f - z) * n + z * hp;
                    hof[br * 512 + jc] = v;
                    st_u16_coh(&hob[br * 512 + jc], f2bf(v));
                }
            }
            gbar4(flags, 96, ++lgen);
        }
    }
}

// ---------------------------------------------------------------------------
// attention for batch b. h read _coh (cross-WG in-kernel); enc reads plain
// (inter-kernel handoff).
// ---------------------------------------------------------------------------
__device__ void attention(int b, const float* __restrict__ hvec,
                          const unsigned short* __restrict__ encb,
                          unsigned short* __restrict__ c_bf,
                          float* hsh, float* ssh)
{
    const int tid = threadIdx.x;
    hsh[tid]       = ld_f32_coh(&hvec[(size_t)b * 512 + tid]);
    hsh[256 + tid] = ld_f32_coh(&hvec[(size_t)b * 512 + 256 + tid]);
    __syncthreads();
    const int wv = tid >> 6, lane = tid & 63;
    float hreg[8];
#pragma unroll
    for (int q = 0; q < 8; ++q) hreg[q] = hsh[lane * 8 + q];
#pragma unroll 4
    for (int i = wv; i < 80; i += 4) {
        bf16x8 v = *(const bf16x8*)&encb[(size_t)i * 65536 + b * 512 + lane * 8];
        float p = 0.f;
#pragma unroll
        for (int q = 0; q < 8; ++q) p += bf2f((unsigned short)v[q]) * hreg[q];
#pragma unroll
        for (int off = 32; off > 0; off >>= 1) p += __shfl_xor(p, off, 64);
        if (lane == 0) ssh[i] = tanhf(p);
    }
    __syncthreads();
    if (tid == 0) {
        float mx = -1e30f;
        for (int i = 0; i < 80; ++i) mx = fmaxf(mx, ssh[i]);
        float s = 0.f;
        for (int i = 0; i < 80; ++i) { float e = expf(ssh[i] - mx); ssh[i] = e; s += e; }
        ssh[80] = 1.0f / s;
    }
    __syncthreads();
    float acc0 = 0.f, acc1 = 0.f;
    const unsigned short* ebase = encb + (size_t)b * 512 + tid * 2;
#pragma unroll 10
    for (int i = 0; i < 80; ++i) {
        unsigned int u = *reinterpret_cast<const unsigned int*>(&ebase[(size_t)i * 65536]);
        float w = ssh[i];
        acc0 += w * __builtin_bit_cast(float, u << 16);
        acc1 += w * __builtin_bit_cast(float, u & 0xffff0000u);
    }
    float inv = ssh[80];
    st_u16_coh(&c_bf[(size_t)b * 512 + tid * 2],     f2bf(acc0 * inv));
    st_u16_coh(&c_bf[(size_t)b * 512 + tid * 2 + 1], f2bf(acc1 * inv));
    __syncthreads();
}

// ---------------------------------------------------------------------------
// Persistent decoder: 25 steps x 3 phases; batched coherent loads throughout.
// ---------------------------------------------------------------------------
__global__ __launch_bounds__(256, 1)
void decode_persist(const unsigned short* __restrict__ encout_bf,
                    const unsigned short* __restrict__ decwih_bf, const unsigned short* __restrict__ decwhh_bf,
                    const float* __restrict__ dec_bih, const float* __restrict__ dec_bhh,
                    const unsigned short* __restrict__ outw_bf, const float* __restrict__ out_b,
                    const float* __restrict__ embed, const int* __restrict__ tgt,
                    const float* __restrict__ hDf, const unsigned short* __restrict__ hDb,
                    float* __restrict__ hCf, unsigned short* __restrict__ hCb,
                    unsigned short* __restrict__ d_bf, unsigned short* __restrict__ c_bf,
                    unsigned long long* __restrict__ pA, unsigned long long* __restrict__ pB,
                    float* __restrict__ out,
                    int* flags)
{
    __shared__ float hsh[512];
    __shared__ float ssh[88];
    __shared__ float sM[128];
    __shared__ int   sI[128];
    __shared__ float sL[128];

    const int g = blockIdx.x;          // 0..127
    const int tid = threadIdx.x, w = tid >> 6, lane = tid & 63;
    const int l15 = lane & 15, kg = lane >> 4;
    int lgen = 0;
    float loss_acc = 0.f;

    // ---- pre-phase: attention_0 from alpha; d_0 = embed[BOS]
    attention(g, hDf, encout_bf, c_bf, hsh, ssh);
    for (int t = tid; t < 512; t += 256)
        st_u16_coh(&d_bf[(size_t)g * 512 + t], f2bf(embed[(size_t)BOS * 512 + t]));
    gbar4(flags, 128, ++lgen);

    for (int j = 0; j < 25; ++j) {
        const float* h_in_f = (j == 0) ? hDf : hCf + (size_t)((j - 1) & 1) * 65536;
        const unsigned short* h_in_b = (j == 0) ? hDb : hCb + (size_t)((j - 1) & 1) * 65536;
        float* h_out_f = hCf + (size_t)(j & 1) * 65536;
        unsigned short* h_out_b = hCb + (size_t)(j & 1) * 65536;

        // ---- P1: GRU step j (WGs 0..63)
        if (g < 64) {
            const int cg = g >> 2, rq = g & 3;
            const int rt = w >> 1, cs = w & 1;
            const int mb = rq * 32 + rt * 16;
            const int jc = cg * 32 + cs * 16 + l15;
            int wrow[3];
#pragma unroll
            for (int t = 0; t < 3; ++t) wrow[t] = t * 512 + cg * 32 + cs * 16 + l15;

            f32x4 agi[3], agh[3];
#pragma unroll
            for (int t = 0; t < 3; ++t) { agi[t] = f32x4{0.f,0.f,0.f,0.f}; agh[t] = f32x4{0.f,0.f,0.f,0.f}; }
            bf16x8 areg[16];

            // seg 0: d (coh, batched)
#pragma unroll
            for (int ks = 0; ks < 16; ++ks)
                areg[ks] = ld_bf8_coh(&d_bf[(size_t)(mb + l15) * 512 + ks * 32 + kg * 8]);
#pragma unroll
            for (int ks = 0; ks < 16; ++ks)
#pragma unroll
                for (int t = 0; t < 3; ++t) {
                    bf16x8 bv = *(const bf16x8*)&decwih_bf[(size_t)wrow[t] * 1536 + 0 + ks * 32 + kg * 8];
                    agi[t] = __builtin_amdgcn_mfma_f32_16x16x32_bf16(areg[ks], bv, agi[t], 0, 0, 0);
                }
            // seg 1: enc tail (plain, inter-kernel)
            const unsigned short* et = encout_bf + (size_t)(80 + j) * 65536;
#pragma unroll 4
            for (int ks = 0; ks < 16; ++ks) {
                bf16x8 a = *(const bf16x8*)&et[(size_t)(mb + l15) * 512 + ks * 32 + kg * 8];
#pragma unroll
                for (int t = 0; t < 3; ++t) {
                    bf16x8 bv = *(const bf16x8*)&decwih_bf[(size_t)wrow[t] * 1536 + 512 + ks * 32 + kg * 8];
                    agi[t] = __builtin_amdgcn_mfma_f32_16x16x32_bf16(a, bv, agi[t], 0, 0, 0);
                }
            }
            // seg 2: context c (coh, batched)
#pragma unroll
            for (int ks = 0; ks < 16; ++ks)
                areg[ks] = ld_bf8_coh(&c_bf[(size_t)(mb + l15) * 512 + ks * 32 + kg * 8]);
#pragma unroll
            for (int ks = 0; ks < 16; ++ks)
#pragma unroll
                for (int t = 0; t < 3; ++t) {
                    bf16x8 bv = *(const bf16x8*)&decwih_bf[(size_t)wrow[t] * 1536 + 1024 + ks * 32 + kg * 8];
                    agi[t] = __builtin_amdgcn_mfma_f32_16x16x32_bf16(areg[ks], bv, agi[t], 0, 0, 0);
                }
            // gh: h_in (coh, batched)
#pragma unroll
            for (int ks = 0; ks < 16; ++ks)
                areg[ks] = ld_bf8_coh(&h_in_b[(size_t)(mb + l15) * 512 + ks * 32 + kg * 8]);
#pragma unroll
            for (int ks = 0; ks < 16; ++ks)
#pragma unroll
                for (int t = 0; t < 3; ++t) {
                    bf16x8 bv = *(const bf16x8*)&decwhh_bf[(size_t)wrow[t] * 512 + ks * 32 + kg * 8];
                    agh[t] = __builtin_amdgcn_mfma_f32_16x16x32_bf16(areg[ks], bv, agh[t], 0, 0, 0);
                }

            float bir = dec_bih[jc], bhr = dec_bhh[jc];
            float biz = dec_bih[512 + jc], bhz = dec_bhh[512 + jc];
            float bin_ = dec_bih[1024 + jc], bhn = dec_bhh[1024 + jc];
            float hpv[4];
#pragma unroll
            for (int rr = 0; rr < 4; ++rr)
                hpv[rr] = ld_f32_coh(&h_in_f[(size_t)(mb + kg * 4 + rr) * 512 + jc]);
#pragma unroll
            for (int rr = 0; rr < 4; ++rr) {
                int br = mb + kg * 4 + rr;
                float r = sigf(agi[0][rr] + bir + agh[0][rr] + bhr);
                float z = sigf(agi[1][rr] + biz + agh[1][rr] + bhz);
                float n = tanhf(agi[2][rr] + bin_ + r * (agh[2][rr] + bhn));
                float v = (1.f - z) * n + z * hpv[rr];
                st_f32_coh(&h_out_f[(size_t)br * 512 + jc], v);
                st_u16_coh(&h_out_b[(size_t)br * 512 + jc], f2bf(v));
            }
        }
        gbar4(flags, 128, ++lgen);

        // ---- P2: logits slice (cols g*32..g*32+31) -> softmax partials; attention_{j+1}
        {
            const int n0 = g * 32;
            f32x4 acc[2][2];
#pragma unroll
            for (int mt = 0; mt < 2; ++mt)
#pragma unroll
                for (int nt = 0; nt < 2; ++nt) acc[mt][nt] = f32x4{0.f,0.f,0.f,0.f};
            bf16x8 ar0[16], ar1[16];
#pragma unroll
            for (int ks = 0; ks < 16; ++ks)
                ar0[ks] = ld_bf8_coh(&h_out_b[(size_t)(w * 32 + l15) * 512 + ks * 32 + kg * 8]);
#pragma unroll
            for (int ks = 0; ks < 16; ++ks)
                ar1[ks] = ld_bf8_coh(&h_out_b[(size_t)(w * 32 + 16 + l15) * 512 + ks * 32 + kg * 8]);
#pragma unroll
            for (int ks = 0; ks < 16; ++ks) {
                bf16x8 b0 = *(const bf16x8*)&outw_bf[(size_t)(n0 + l15) * 512 + ks * 32 + kg * 8];
                bf16x8 b1 = *(const bf16x8*)&outw_bf[(size_t)(n0 + 16 + l15) * 512 + ks * 32 + kg * 8];
                acc[0][0] = __builtin_amdgcn_mfma_f32_16x16x32_bf16(ar0[ks], b0, acc[0][0], 0, 0, 0);
                acc[0][1] = __builtin_amdgcn_mfma_f32_16x16x32_bf16(ar0[ks], b1, acc[0][1], 0, 0, 0);
                acc[1][0] = __builtin_amdgcn_mfma_f32_16x16x32_bf16(ar1[ks], b0, acc[1][0], 0, 0, 0);
                acc[1][1] = __builtin_amdgcn_mfma_f32_16x16x32_bf16(ar1[ks], b1, acc[1][1], 0, 0, 0);
            }
            float ob0 = out_b[n0 + l15], ob1 = out_b[n0 + 16 + l15];
#pragma unroll
            for (int mt = 0; mt < 2; ++mt) {
#pragma unroll
                for (int rr = 0; rr < 4; ++rr) {
                    int m = w * 32 + mt * 16 + kg * 4 + rr;     // batch row
                    float v0 = acc[mt][0][rr] + ob0;            // col n0+l15
                    float v1 = acc[mt][1][rr] + ob1;            // col n0+16+l15
                    int tj = tgt[m * 25 + j];
                    float pm; int pi;
                    if (v0 >= v1) { pm = v0; pi = n0 + l15; }
                    else          { pm = v1; pi = n0 + 16 + l15; }
                    float pl = -1e30f;
                    if (n0 + l15 == tj)      pl = v0;
                    if (n0 + 16 + l15 == tj) pl = v1;
#pragma unroll
                    for (int off = 1; off < 16; off <<= 1) {
                        float om = __shfl_xor(pm, off, 64);
                        int   oi = __shfl_xor(pi, off, 64);
                        float ol = __shfl_xor(pl, off, 64);
                        if (om > pm || (om == pm && oi < pi)) { pm = om; pi = oi; }
                        pl = fmaxf(pl, ol);
                    }
                    float ps = expf(v0 - pm) + expf(v1 - pm);
#pragma unroll
                    for (int off = 1; off < 16; off <<= 1) ps += __shfl_xor(ps, off, 64);
                    if (l15 == 0) {
                        st_u64_coh(&pA[(size_t)m * 128 + g], pack_ff(pm, ps));
                        st_u64_coh(&pB[(size_t)m * 128 + g], pack_if(pi, pl));
                    }
                }
            }
            if (j < 24) attention(g, h_out_f, encout_bf, c_bf, hsh, ssh);
        }
        gbar4(flags, 128, ++lgen);

        // ---- P3: combine partials for batch b=g; loss + argmax feedback
        {
            const int b = g;
            float m_ = -1e30f, s_ = 0.f, l_ = -1e30f; int i_ = 0x7fffffff;
            if (tid < 128) {
                unsigned long long ua = ld_u64_coh(&pA[(size_t)b * 128 + tid]);
                unsigned long long ub = ld_u64_coh(&pB[(size_t)b * 128 + tid]);
                m_ = __builtin_bit_cast(float, (unsigned int)ua);
                s_ = __builtin_bit_cast(float, (unsigned int)(ua >> 32));
                i_ = (int)(unsigned int)ub;
                l_ = __builtin_bit_cast(float, (unsigned int)(ub >> 32));
            }
            if (tid < 128) { sM[tid] = m_; sI[tid] = i_; sL[tid] = l_; }
            __syncthreads();
            for (int s = 64; s > 0; s >>= 1) {
                if (tid < s) {
                    float om = sM[tid + s]; int oi = sI[tid + s];
                    if (om > sM[tid] || (om == sM[tid] && oi < sI[tid])) { sM[tid] = om; sI[tid] = oi; }
                    sL[tid] = fmaxf(sL[tid], sL[tid + s]);
                }
                __syncthreads();
            }
            float M = sM[0]; float LT = sL[0];
            int gidx = sI[0];
            __syncthreads();
            if (tid < 128) sM[tid] = s_ * expf(m_ - M);
            __syncthreads();
            for (int s = 64; s > 0; s >>= 1) {
                if (tid < s) sM[tid] += sM[tid + s];
                __syncthreads();
            }
            if (tid == 0) {
                float lse = M + logf(sM[0]);
                loss_acc += -(LT - lse);
            }
            for (int t = tid; t < 512; t += 256)
                st_u16_coh(&d_bf[(size_t)b * 512 + t], f2bf(embed[(size_t)gidx * 512 + t]));
            __syncthreads();
        }
        gbar4(flags, 128, ++lgen);
    }

    if (tid == 0) atomicAdd(out, loss_acc * (1.0f / 3200.0f));
}

// fp32 -> bf16 cast (n multiple of 1024)
__global__ void cast_f2b(const float* __restrict__ in, unsigned short* __restrict__ out, int n)
{
    int i = (blockIdx.x * 256 + threadIdx.x) * 4;
    if (i < n) {
        float4 v = *reinterpret_cast<const float4*>(&in[i]);
        out[i + 0] = f2bf(v.x); out[i + 1] = f2bf(v.y);
        out[i + 2] = f2bf(v.z); out[i + 3] = f2bf(v.w);
    }
}

// ---------------------------------------------------------------------------
extern "C" void kernel_launch(void* const* d_in, const int* in_sizes, int n_in,
                              void* d_out, int out_size, void* d_ws, size_t ws_size,
                              hipStream_t stream)
{
    const float* feats   = (const float*)d_in[0];
    const float* fc_w    = (const float*)d_in[1];
    const float* fc_b    = (const float*)d_in[2];
    const float* enc_wih = (const float*)d_in[3];
    const float* enc_whh = (const float*)d_in[4];
    const float* enc_bih = (const float*)d_in[5];
    const float* enc_bhh = (const float*)d_in[6];
    const float* dec_wih = (const float*)d_in[7];
    const float* dec_whh = (const float*)d_in[8];
    const float* dec_bih = (const float*)d_in[9];
    const float* dec_bhh = (const float*)d_in[10];
    const float* out_w   = (const float*)d_in[11];
    const float* out_b   = (const float*)d_in[12];
    const float* embed   = (const float*)d_in[13];
    const int*   tgt     = (const int*)d_in[14];

    float* ws = (float*)d_ws;
    size_t off = 0;
    auto afl = [&](size_t n) { float* r = ws + off; off += n; return r; };

    float* enc_gi            = afl(15728640);              // [80][128][1536] fp32
    float* enc_out           = afl(6881280);               // [105][128][512] fp32
    unsigned short* encout_bf = (unsigned short*)afl(3440640);
    unsigned short* xp_bf     = (unsigned short*)afl(2621440);
    unsigned short* fcw_bf    = (unsigned short*)afl(1048576);
    unsigned short* encwih_bf = (unsigned short*)afl(393216);
    unsigned short* encwhh_bf = (unsigned short*)afl(393216);
    unsigned short* decwih_bf = (unsigned short*)afl(1179648);  // full 1536x1536
    unsigned short* decwhh_bf = (unsigned short*)afl(393216);
    unsigned short* outw_bf   = (unsigned short*)afl(1048576);
    unsigned short* h0b       = (unsigned short*)afl(32768);    // zeros bf16
    float* hDf               = afl(131072);                // [2][128][512]
    unsigned short* hDb       = (unsigned short*)afl(65536);
    float* hCf               = afl(131072);
    unsigned short* hCb       = (unsigned short*)afl(65536);
    unsigned short* d_bf      = (unsigned short*)afl(32768);
    unsigned short* c_bf      = (unsigned short*)afl(32768);
    unsigned long long* pA   = (unsigned long long*)afl(32768); // [128][128] u64
    unsigned long long* pB   = (unsigned long long*)afl(32768);
    int*   bar               = (int*)afl(8192);            // barrier flags

    int* flagsR = bar;                 // 96 * 32 ints
    int* flagsD = bar + 4096;          // 128 * 32 ints

    hipMemsetAsync(h0b, 0, 65536 * sizeof(unsigned short), stream);
    hipMemsetAsync(bar, 0, 8192 * sizeof(int), stream);
    hipMemsetAsync(d_out, 0, sizeof(float), stream);

    cast_f2b<<<2048, 256, 0, stream>>>(fc_w, fcw_bf, 2097152);
    cast_f2b<<<768, 256, 0, stream>>>(enc_wih, encwih_bf, 786432);
    cast_f2b<<<768, 256, 0, stream>>>(enc_whh, encwhh_bf, 786432);
    cast_f2b<<<2304, 256, 0, stream>>>(dec_wih, decwih_bf, 2359296);
    cast_f2b<<<768, 256, 0, stream>>>(dec_whh, decwhh_bf, 786432);
    cast_f2b<<<2048, 256, 0, stream>>>(out_w, outw_bf, 2097152);

    // fc: xp_bf = leaky_relu(feats @ fc_w^T + fc_b)   M=10240 K=4096 N=512
    gemm_mfma<1, 1, 1><<<dim3(4, 80), 256, 0, stream>>>(feats, 4096, fcw_bf, 4096, fc_b, xp_bf, 512, 4096);
    // enc gi (t<80): xp @ enc_wih^T + enc_bih   M=10240 K=512 N=1536
    gemm_mfma<0, 0, 0><<<dim3(12, 80), 256, 0, stream>>>(xp_bf, 512, encwih_bf, 512, enc_bih, enc_gi, 1536, 512);

    recur_persist<<<96, 256, 0, stream>>>(enc_gi, enc_bih, enc_bhh, encwhh_bf,
                                          decwih_bf, decwhh_bf, dec_bih, dec_bhh,
                                          h0b, enc_out, encout_bf, hDf, hDb,
                                          flagsR);

    decode_persist<<<128, 256, 0, stream>>>(encout_bf, decwih_bf, decwhh_bf,
                                            dec_bih, dec_bhh, outw_bf, out_b,
                                            embed, tgt, hDf, hDb, hCf, hCb,
                                            d_bf, c_bf, pA, pB, (float*)d_out,
                                            flagsD);
}